// Round 8
// baseline (294.822 us; speedup 1.0000x reference)
//
#include <hip/hip_runtime.h>
#include <math.h>

#define NNODES 50000
#define NEDGES 262144
#define NEG_SLOPE 0.2f
#define NBINS (2 * NNODES)
#define NXP64 782                   // ceil(50000/64)
#define NWG_GEMM (2 * NXP64 * 12)   // 18768 (divisible by 8)

typedef __attribute__((ext_vector_type(8))) short short8;   // 8 x bf16 (16B)
typedef __attribute__((ext_vector_type(4))) float f32x4;    // MFMA acc
typedef __attribute__((ext_vector_type(2))) float f32x2;
typedef __attribute__((ext_vector_type(4))) unsigned short u16x4;

// aux layout (floats): [0,2N) ps per rel (rel*N+src) ; [2N,4N) pd per rel ;
//                      [4N,6N) hl per type (t*N+node) ; [6N,8N) hr per type
#define AUX_PS 0
#define AUX_PD (2 * NNODES)
#define AUX_HL (4 * NNODES)
#define AUX_HR (6 * NNODES)

// ---------- helpers ----------
__device__ __forceinline__ float elu_f(float x) { return x > 0.f ? x : (__expf(x) - 1.f); }
__device__ __forceinline__ float bf2f(unsigned short u) {
    return __uint_as_float(((unsigned)u) << 16);
}
__device__ __forceinline__ f32x2 bfp2f(unsigned p) {   // 2 packed bf16 -> 2 f32
    f32x2 r;
    r.x = __uint_as_float(p << 16);
    r.y = __uint_as_float(p & 0xffff0000u);
    return r;
}
__device__ __forceinline__ unsigned short f2bf(float f) {
    unsigned u = __float_as_uint(f);
    unsigned r = (u + 0x7fffu + ((u >> 16) & 1u)) >> 16;   // RNE
    return (unsigned short)r;
}

// ---------- f32 -> bf16 convert (hA and hB in one dispatch) ----------
__global__ __launch_bounds__(256) void conv_bf16_2(const float* __restrict__ inA,
                                                   const float* __restrict__ inB,
                                                   unsigned short* __restrict__ outA,
                                                   unsigned short* __restrict__ outB,
                                                   int half) {
    int i = (blockIdx.x * 256 + threadIdx.x) * 4;
    if (i >= 2 * half) return;
    const float* in = (i < half) ? inA : inB;
    unsigned short* out = (i < half) ? outA : outB;
    int k = (i < half) ? i : i - half;
    float4 v = *reinterpret_cast<const float4*>(&in[k]);
    u16x4 o;
    o[0] = f2bf(v.x); o[1] = f2bf(v.y); o[2] = f2bf(v.z); o[3] = f2bf(v.w);
    *reinterpret_cast<u16x4*>(&out[k]) = o;
}

// ---------- merged: precompute u_l/u_r/c_l/c_r (blocks 0-1) + weight pack (blocks 2..1537)
__global__ __launch_bounds__(256) void prep_all(
    const float* __restrict__ Wself, const float* __restrict__ Wsrc, const float* __restrict__ Wdst,
    const float* __restrict__ bself, const float* __restrict__ bsrc, const float* __restrict__ bdst,
    const float* __restrict__ Wq, const float* __restrict__ bq,
    const float* __restrict__ Wk, const float* __restrict__ bk,
    const float* __restrict__ Wal, const float* __restrict__ bal,
    const float* __restrict__ War, const float* __restrict__ bar,
    unsigned short* __restrict__ Wt, float* __restrict__ biasF,
    float* __restrict__ u_l, float* __restrict__ u_r,
    float* __restrict__ c_l, float* __restrict__ c_r) {
    if (blockIdx.x < 2) {
        int t = blockIdx.x;
        int d = threadIdx.x;
        float sl = 0.f, sr = 0.f;
        for (int j = 0; j < 64; ++j) {
            sl += Wk[((size_t)t * 256 + d) * 64 + j] * Wal[t * 64 + j];
            sr += Wq[((size_t)t * 256 + d) * 64 + j] * War[t * 64 + j];
        }
        u_l[t * 256 + d] = sl;
        u_r[t * 256 + d] = sr;
        if (d == 0) {
            float cl = bal[t], cr = bar[t];
            for (int j = 0; j < 64; ++j) {
                cl += bk[t * 64 + j] * Wal[t * 64 + j];
                cr += bq[t * 64 + j] * War[t * 64 + j];
            }
            c_l[t] = cl; c_r[t] = cr;
        }
        return;
    }
    int r = blockIdx.x - 2;        // 0..1535 = t*768 + n
    int t = r / 768;
    int n = r % 768;
    int seg = n >> 8;
    int nn = n & 255;
    const float* W; const float* bv; int ti;
    if (seg == 0)      { W = Wself; bv = bself; ti = t; }
    else if (seg == 1) { W = Wsrc;  bv = bsrc;  ti = t; }
    else               { W = Wdst;  bv = bdst;  ti = 1 - t; }
    int k = threadIdx.x;
    float val = W[(size_t)ti * 65536 + (size_t)k * 256 + nn];
    Wt[(size_t)r * 256 + k] = f2bf(val);
    if (k == 0) biasF[r] = bv[ti * 256 + nn];
}

// ---------- counting sort (both relations per dispatch) ----------
__global__ __launch_bounds__(256) void hist2(const int* __restrict__ dab,
                                             const int* __restrict__ dba,
                                             int* __restrict__ counts) {
    int e = blockIdx.x * 256 + threadIdx.x;
    if (e < NEDGES) atomicAdd(&counts[dab[e]], 1);
    else if (e < 2 * NEDGES) atomicAdd(&counts[NNODES + dba[e - NEDGES]], 1);
}

__global__ __launch_bounds__(256) void scan1(const int* __restrict__ counts,
                                             int* __restrict__ incl,
                                             int* __restrict__ bsum, int n) {
    __shared__ int s[256];
    int i = blockIdx.x * 256 + threadIdx.x;
    int t = threadIdx.x;
    s[t] = (i < n) ? counts[i] : 0;
    __syncthreads();
#pragma unroll
    for (int off = 1; off < 256; off <<= 1) {
        int x = (t >= off) ? s[t - off] : 0;
        __syncthreads();
        s[t] += x;
        __syncthreads();
    }
    if (i < n) incl[i] = s[t];
    if (t == 255) bsum[blockIdx.x] = s[255];
}

__global__ __launch_bounds__(512) void scan2(int* __restrict__ bsum, int nb) {
    __shared__ int s[512];
    int t = threadIdx.x;
    s[t] = (t < nb) ? bsum[t] : 0;
    __syncthreads();
#pragma unroll
    for (int off = 1; off < 512; off <<= 1) {
        int x = (t >= off) ? s[t - off] : 0;
        __syncthreads();
        s[t] += x;
        __syncthreads();
    }
    if (t < nb) bsum[t] = s[t];
}

__global__ __launch_bounds__(256) void scan3(const int* __restrict__ counts,
                                             int* __restrict__ incl_to_excl,
                                             const int* __restrict__ bsum,
                                             int* __restrict__ cursor, int n) {
    int i = blockIdx.x * 256 + threadIdx.x;
    if (i >= n) return;
    int base = (blockIdx.x > 0) ? bsum[blockIdx.x - 1] : 0;
    int st = base + incl_to_excl[i] - counts[i];
    incl_to_excl[i] = st;
    cursor[i] = st;
}

__global__ __launch_bounds__(256) void scatter2(const int* __restrict__ sab,
                                                const int* __restrict__ dab,
                                                const int* __restrict__ sba,
                                                const int* __restrict__ dba,
                                                int* __restrict__ cursor,
                                                int* __restrict__ sorted_src) {
    int e = blockIdx.x * 256 + threadIdx.x;
    if (e < NEDGES) {
        int pos = atomicAdd(&cursor[dab[e]], 1);
        sorted_src[pos] = sab[e];
    } else if (e < 2 * NEDGES) {
        int k = e - NEDGES;
        int pos = atomicAdd(&cursor[NNODES + dba[k]], 1);
        sorted_src[pos] = sba[k];
    }
}

// ---------- 1-wave bf16 MFMA GEMM: 64x64 tile, BK=32, ZERO barriers,
// counted-vmcnt double-buffer (2 tiles in flight), aux node-dot epilogue.
// Waves are fully independent -> no lockstep barrier cascades.
__global__ __launch_bounds__(64) void gemm_mfma(
    const unsigned short* __restrict__ hAb,
    const unsigned short* __restrict__ hBb,
    const unsigned short* __restrict__ Wt,
    const float* __restrict__ biasF,
    const float* __restrict__ attn_v,
    const float* __restrict__ u_l,
    const float* __restrict__ u_r,
    unsigned short* __restrict__ bufA,
    unsigned short* __restrict__ bufB,
    float* __restrict__ aux,
    int M)
{
    __shared__ unsigned short lds[8192];   // 16KB: A bufs @0,2048 ; B bufs @4096,6144
    const int lane = threadIdx.x;

    // exact XCD swizzle (NWG_GEMM % 8 == 0): consecutive wgid -> same XCD
    const int cpx = NWG_GEMM / 8;
    int orig = blockIdx.x;
    int wgid = (orig & 7) * cpx + (orig >> 3);
    int t   = wgid / (NXP64 * 12);
    int rem = wgid % (NXP64 * 12);
    int xp  = rem / 12;          // A row-panel (yc fastest => 12 consecutive share panel)
    int yc  = rem % 12;          // 64-col panel within 768

    const int row0 = xp * 64;
    const int col0 = yc * 64;
    const unsigned short* Ain = t ? hBb : hAb;
    const unsigned short* Wtt = Wt + (size_t)t * 768 * 256;
    const float* bias = biasF + t * 768;
    unsigned short* Cout = t ? bufB : bufA;

    f32x4 acc[4][4] = {};

    // staging sources: chunk c = rr*64+lane; row=c>>2, slot=c&3,
    // fetch k-chunk kc = slot ^ ((row>>1)&3) (both-sides swizzle)
    const unsigned short* gA[4];
    const unsigned short* gB[4];
#pragma unroll
    for (int rr = 0; rr < 4; ++rr) {
        int c = rr * 64 + lane;
        int row = c >> 2;
        int kc = (c & 3) ^ ((row >> 1) & 3);
        int ga = min(row0 + row, M - 1);          // clamp OOB rows (store guarded)
        gA[rr] = Ain + (size_t)ga * 256 + kc * 8;
        gB[rr] = Wtt + (size_t)(col0 + row) * 256 + kc * 8;
    }

#define STAGE(buf, kt)                                                                   \
    {                                                                                    \
        unsigned short* Ad = lds + (buf) * 2048;                                         \
        unsigned short* Bd = lds + 4096 + (buf) * 2048;                                  \
        _Pragma("unroll")                                                                \
        for (int rr = 0; rr < 4; ++rr) {                                                 \
            __builtin_amdgcn_global_load_lds(                                            \
                (const __attribute__((address_space(1))) unsigned int*)(gA[rr] + (kt)),  \
                (__attribute__((address_space(3))) unsigned int*)(Ad + rr * 512),        \
                16, 0, 0);                                                               \
            __builtin_amdgcn_global_load_lds(                                            \
                (const __attribute__((address_space(1))) unsigned int*)(gB[rr] + (kt)),  \
                (__attribute__((address_space(3))) unsigned int*)(Bd + rr * 512),        \
                16, 0, 0);                                                               \
        }                                                                                \
    }

    STAGE(0, 0);        // tile 0 (8 loads)
    STAGE(1, 32);       // tile 1 (16 outstanding)

#pragma unroll
    for (int it = 0; it < 8; ++it) {
        const int cur = it & 1;
        // wait this tile's 8 loads; keep next tile's 8 in flight
        if (it < 7) { asm volatile("s_waitcnt vmcnt(8)" ::: "memory"); }
        else        { asm volatile("s_waitcnt vmcnt(0)" ::: "memory"); }
        __builtin_amdgcn_sched_barrier(0);

        const unsigned short* As = lds + cur * 2048;
        const unsigned short* Bs = lds + 4096 + cur * 2048;
        short8 a[4], b[4];
#pragma unroll
        for (int i = 0; i < 4; ++i) {
            int ar = i * 16 + (lane & 15);
            a[i] = *reinterpret_cast<const short8*>(
                &As[ar * 32 + (((lane >> 4) ^ ((ar >> 1) & 3)) << 3)]);
            int br = i * 16 + (lane & 15);
            b[i] = *reinterpret_cast<const short8*>(
                &Bs[br * 32 + (((lane >> 4) ^ ((br >> 1) & 3)) << 3)]);
        }
#pragma unroll
        for (int i = 0; i < 4; ++i)
#pragma unroll
            for (int j = 0; j < 4; ++j)
                acc[i][j] = __builtin_amdgcn_mfma_f32_16x16x32_bf16(a[i], b[j], acc[i][j], 0, 0, 0);

        // own ds_reads drained before overwriting cur (single wave: no barrier needed)
        asm volatile("s_waitcnt lgkmcnt(0)" ::: "memory");
        __builtin_amdgcn_sched_barrier(0);
        if (it < 6) STAGE(cur, (it + 2) * 32);   // stage tile it+2 into cur
    }
#undef STAGE

    // ---- epilogue: acc (+bias) -> LDS [64][64] bf16, XOR col-group by (row>>2)&3
#pragma unroll
    for (int j = 0; j < 4; ++j) {
        int ci = lane & 15;
        float bv = bias[col0 + j * 16 + ci];
#pragma unroll
        for (int i = 0; i < 4; ++i) {
            int rowb = i * 16 + ((lane >> 4) << 2);
#pragma unroll
            for (int v = 0; v < 4; ++v) {
                int row = rowb + v;
                int g2 = j ^ ((row >> 2) & 3);
                lds[row * 64 + g2 * 16 + ci] = f2bf(acc[i][j][v] + bv);
            }
        }
    }

    // which node-dot(s) this 64-col panel contributes to:
    const int seg = yc >> 2;                   // 0:z, 1:ftS, 2:ftD
    const int cq  = yc & 3;                    // 64-col quarter within 256
    const float* avp1; float* axp1;
    const float* avp2 = nullptr; float* axp2 = nullptr;
    if (seg == 0) {
        avp1 = u_l + t * 256;            axp1 = aux + AUX_HL + (size_t)t * NNODES;
        avp2 = u_r + t * 256;            axp2 = aux + AUX_HR + (size_t)t * NNODES;
    } else if (seg == 1) {
        avp1 = attn_v + t * 256;         axp1 = aux + AUX_PS + (size_t)t * NNODES;
    } else {
        avp1 = attn_v + (1 - t) * 256;   axp1 = aux + AUX_PD + (size_t)(1 - t) * NNODES;
    }

    // coalesced stores (16B/lane) + per-row aux partials (8 lanes/row)
#pragma unroll
    for (int p = 0; p < 8; ++p) {
        int c = p * 64 + lane;
        int row = c >> 3;
        int ch = c & 7;                          // 16B chunk within row
        int g2 = (ch >> 1) ^ ((row >> 2) & 3);
        int grow = row0 + row;
        bool ok = grow < M;
        short8 val = *reinterpret_cast<const short8*>(&lds[row * 64 + g2 * 16 + ((ch & 1) << 3)]);
        if (ok)
            *reinterpret_cast<short8*>(&Cout[(size_t)grow * 768 + col0 + ch * 8]) = val;
        int colb = cq * 64 + ch * 8;
        float4 w0v = *reinterpret_cast<const float4*>(&avp1[colb]);
        float4 w1v = *reinterpret_cast<const float4*>(&avp1[colb + 4]);
        float p1 = w0v.x * bf2f((unsigned short)val[0]) + w0v.y * bf2f((unsigned short)val[1])
                 + w0v.z * bf2f((unsigned short)val[2]) + w0v.w * bf2f((unsigned short)val[3])
                 + w1v.x * bf2f((unsigned short)val[4]) + w1v.y * bf2f((unsigned short)val[5])
                 + w1v.z * bf2f((unsigned short)val[6]) + w1v.w * bf2f((unsigned short)val[7]);
        p1 += __shfl_xor(p1, 1);
        p1 += __shfl_xor(p1, 2);
        p1 += __shfl_xor(p1, 4);
        if (ch == 0 && ok) atomicAdd(&axp1[grow], p1);
        if (avp2) {
            float4 y0 = *reinterpret_cast<const float4*>(&avp2[colb]);
            float4 y1 = *reinterpret_cast<const float4*>(&avp2[colb + 4]);
            float p2 = y0.x * bf2f((unsigned short)val[0]) + y0.y * bf2f((unsigned short)val[1])
                     + y0.z * bf2f((unsigned short)val[2]) + y0.w * bf2f((unsigned short)val[3])
                     + y1.x * bf2f((unsigned short)val[4]) + y1.y * bf2f((unsigned short)val[5])
                     + y1.z * bf2f((unsigned short)val[6]) + y1.w * bf2f((unsigned short)val[7]);
            p2 += __shfl_xor(p2, 1);
            p2 += __shfl_xor(p2, 2);
            p2 += __shfl_xor(p2, 4);
            if (ch == 0 && ok) atomicAdd(&axp2[grow], p2);
        }
    }
}

// ---------- fully fused per-dst GATv2 + node attention + combine
// 16 lanes/dst, 4 dsts/wave. lrelu factorization: logit = 0.6(ps+pd) + 0.4*sum(av*|fs+fd|)
// ps/pd/hl/hr precomputed in gemm epilogue (aux). No-max softmax (logits ~N(0,1)).
__global__ __launch_bounds__(256) void gat_fused(
    const unsigned short* __restrict__ bufA, const unsigned short* __restrict__ bufB,
    const int* __restrict__ sorted_src, const int* __restrict__ row_start,
    const int* __restrict__ counts,
    const float* __restrict__ attn_v, const float* __restrict__ gbias,
    const float* __restrict__ u_l,
    const float* __restrict__ c_l, const float* __restrict__ c_r,
    const float* __restrict__ aux,
    float* __restrict__ out)
{
    const int tid = threadIdx.x;
    const int l = tid & 15;            // lane in 16-group
    const int gBase = tid & 48;        // group base lane within wave
    const int nd = blockIdx.x * 16 + (tid >> 4);
    if (nd >= 2 * NNODES) return;
    const int rel = nd >= NNODES;      // 0: ab (dst type B), 1: ba (dst type A)
    const int d = nd - rel * NNODES;
    const int td = rel ? 0 : 1;        // dst node type

    const unsigned short* zbuf = td ? bufB : bufA;
    const unsigned short* ftS = (rel ? bufB : bufA) + 256;
    const unsigned short* ftD = zbuf + 512;
    const float clv = c_l[td], crv = c_r[td];

    // per-lane dims [l*16, l*16+16) as f32x2 pairs
    f32x2 fd2[8], av2[8];
    {
        const unsigned short* fdp = &ftD[(size_t)d * 768 + l * 16];
        uint4 d0 = *reinterpret_cast<const uint4*>(fdp);
        uint4 d1 = *reinterpret_cast<const uint4*>(fdp + 8);
        fd2[0] = bfp2f(d0.x); fd2[1] = bfp2f(d0.y); fd2[2] = bfp2f(d0.z); fd2[3] = bfp2f(d0.w);
        fd2[4] = bfp2f(d1.x); fd2[5] = bfp2f(d1.y); fd2[6] = bfp2f(d1.z); fd2[7] = bfp2f(d1.w);
        const float* avp = attn_v + rel * 256 + l * 16;
#pragma unroll
        for (int e = 0; e < 4; ++e) {
            float4 a = *reinterpret_cast<const float4*>(&avp[e * 4]);
            av2[2 * e].x = a.x; av2[2 * e].y = a.y;
            av2[2 * e + 1].x = a.z; av2[2 * e + 1].y = a.w;
        }
    }

    const float pd6 = 0.6f * aux[AUX_PD + (size_t)rel * NNODES + d];
    const float hlv = aux[AUX_HL + (size_t)td * NNODES + d] + clv;
    const float hrv = aux[AUX_HR + (size_t)td * NNODES + d] + crv;
    const float a0 = elu_f(hlv + hrv);           // att_self (pre-softmax)
    const float* psb = aux + AUX_PS + (size_t)rel * NNODES;

    const int p0  = row_start[nd];
    const int cnt = counts[nd];
    float den = 0.f;
    f32x2 acc2[8];
#pragma unroll
    for (int e = 0; e < 8; ++e) { acc2[e].x = 0.f; acc2[e].y = 0.f; }

    for (int base = 0; base < cnt; base += 16) {
        int nloc = min(16, cnt - base);
        int sv = 0; float psl = 0.f;
        if (base + l < cnt) { sv = sorted_src[p0 + base + l]; psl = psb[sv]; }
        int j = 0;
        for (; j + 2 <= nloc; j += 2) {
            int s0 = __shfl(sv, gBase + j);
            int s1 = __shfl(sv, gBase + j + 1);
            float q0 = __shfl(psl, gBase + j);
            float q1 = __shfl(psl, gBase + j + 1);
            const unsigned short* rp0 = &ftS[(size_t)s0 * 768 + l * 16];
            const unsigned short* rp1 = &ftS[(size_t)s1 * 768 + l * 16];
            uint4 A0 = *reinterpret_cast<const uint4*>(rp0);
            uint4 A1 = *reinterpret_cast<const uint4*>(rp0 + 8);
            uint4 B0 = *reinterpret_cast<const uint4*>(rp1);
            uint4 B1 = *reinterpret_cast<const uint4*>(rp1 + 8);
            f32x2 fa2[8], fb2[8];
            fa2[0] = bfp2f(A0.x); fa2[1] = bfp2f(A0.y); fa2[2] = bfp2f(A0.z); fa2[3] = bfp2f(A0.w);
            fa2[4] = bfp2f(A1.x); fa2[5] = bfp2f(A1.y); fa2[6] = bfp2f(A1.z); fa2[7] = bfp2f(A1.w);
            fb2[0] = bfp2f(B0.x); fb2[1] = bfp2f(B0.y); fb2[2] = bfp2f(B0.z); fb2[3] = bfp2f(B0.w);
            fb2[4] = bfp2f(B1.x); fb2[5] = bfp2f(B1.y); fb2[6] = bfp2f(B1.z); fb2[7] = bfp2f(B1.w);
            float Sa = 0.f, Sb = 0.f;
#pragma unroll
            for (int e = 0; e < 8; ++e) {
                f32x2 xa = fa2[e] + fd2[e];
                f32x2 xb = fb2[e] + fd2[e];
                Sa += av2[e].x * fabsf(xa.x);
                Sa += av2[e].y * fabsf(xa.y);
                Sb += av2[e].x * fabsf(xb.x);
                Sb += av2[e].y * fabsf(xb.y);
            }
            Sa += __shfl_xor(Sa, 1); Sb += __shfl_xor(Sb, 1);
            Sa += __shfl_xor(Sa, 2); Sb += __shfl_xor(Sb, 2);
            Sa += __shfl_xor(Sa, 4); Sb += __shfl_xor(Sb, 4);
            Sa += __shfl_xor(Sa, 8); Sb += __shfl_xor(Sb, 8);
            float wa = __expf(fmaf(0.6f, q0, pd6) + 0.4f * Sa);
            float wb = __expf(fmaf(0.6f, q1, pd6) + 0.4f * Sb);
            den += wa + wb;
#pragma unroll
            for (int e = 0; e < 8; ++e) acc2[e] += wa * fa2[e] + wb * fb2[e];
        }
        if (j < nloc) {
            int s0 = __shfl(sv, gBase + j);
            float q0 = __shfl(psl, gBase + j);
            const unsigned short* rp0 = &ftS[(size_t)s0 * 768 + l * 16];
            uint4 A0 = *reinterpret_cast<const uint4*>(rp0);
            uint4 A1 = *reinterpret_cast<const uint4*>(rp0 + 8);
            f32x2 fa2[8];
            fa2[0] = bfp2f(A0.x); fa2[1] = bfp2f(A0.y); fa2[2] = bfp2f(A0.z); fa2[3] = bfp2f(A0.w);
            fa2[4] = bfp2f(A1.x); fa2[5] = bfp2f(A1.y); fa2[6] = bfp2f(A1.z); fa2[7] = bfp2f(A1.w);
            float Sa = 0.f;
#pragma unroll
            for (int e = 0; e < 8; ++e) {
                f32x2 xa = fa2[e] + fd2[e];
                Sa += av2[e].x * fabsf(xa.x);
                Sa += av2[e].y * fabsf(xa.y);
            }
            Sa += __shfl_xor(Sa, 1);
            Sa += __shfl_xor(Sa, 2);
            Sa += __shfl_xor(Sa, 4);
            Sa += __shfl_xor(Sa, 8);
            float wa = __expf(fmaf(0.6f, q0, pd6) + 0.4f * Sa);
            den += wa;
#pragma unroll
            for (int e = 0; e < 8; ++e) acc2[e] += wa * fa2[e];
        }
    }

    // ---- finalize rst row: v = acc/den + gbias
    float inv = den > 0.f ? 1.f / den : 1.f;
    const float* gb = gbias + rel * 256 + l * 16;
    const float* ulp = u_l + td * 256 + l * 16;
    f32x2 v2[8];
    float dotv = 0.f;
#pragma unroll
    for (int e = 0; e < 4; ++e) {
        float4 g = *reinterpret_cast<const float4*>(&gb[e * 4]);
        float4 u = *reinterpret_cast<const float4*>(&ulp[e * 4]);
        v2[2 * e].x     = acc2[2 * e].x     * inv + g.x;
        v2[2 * e].y     = acc2[2 * e].y     * inv + g.y;
        v2[2 * e + 1].x = acc2[2 * e + 1].x * inv + g.z;
        v2[2 * e + 1].y = acc2[2 * e + 1].y * inv + g.w;
        dotv += v2[2 * e].x * u.x + v2[2 * e].y * u.y
              + v2[2 * e + 1].x * u.z + v2[2 * e + 1].y * u.w;
    }
    dotv += __shfl_xor(dotv, 1);
    dotv += __shfl_xor(dotv, 2);
    dotv += __shfl_xor(dotv, 4);
    dotv += __shfl_xor(dotv, 8);
    const float ea = elu_f(dotv + clv + hrv);

    // ---- 2-way softmax combine + final elu, write output row
    float mx = fmaxf(a0, ea);
    float e0 = __expf(a0 - mx), e1 = __expf(ea - mx);
    float is = 1.f / (e0 + e1);
    float w0 = e0 * is, w1 = e1 * is;

    const unsigned short* zrow = zbuf + (size_t)d * 768 + l * 16;
    uint4 z0 = *reinterpret_cast<const uint4*>(zrow);
    uint4 z1 = *reinterpret_cast<const uint4*>(zrow + 8);
    f32x2 zf2[8];
    zf2[0] = bfp2f(z0.x); zf2[1] = bfp2f(z0.y); zf2[2] = bfp2f(z0.z); zf2[3] = bfp2f(z0.w);
    zf2[4] = bfp2f(z1.x); zf2[5] = bfp2f(z1.y); zf2[6] = bfp2f(z1.z); zf2[7] = bfp2f(z1.w);

    float* orow = out + ((size_t)(1 - rel) * NNODES + d) * 256 + l * 16;
#pragma unroll
    for (int e = 0; e < 4; ++e) {
        float4 o;
        o.x = elu_f(w0 * zf2[2 * e].x     + w1 * v2[2 * e].x);
        o.y = elu_f(w0 * zf2[2 * e].y     + w1 * v2[2 * e].y);
        o.z = elu_f(w0 * zf2[2 * e + 1].x + w1 * v2[2 * e + 1].x);
        o.w = elu_f(w0 * zf2[2 * e + 1].y + w1 * v2[2 * e + 1].y);
        *reinterpret_cast<float4*>(&orow[e * 4]) = o;
    }
}

extern "C" void kernel_launch(void* const* d_in, const int* in_sizes, int n_in,
                              void* d_out, int out_size, void* d_ws, size_t ws_size,
                              hipStream_t stream) {
    const float* hA     = (const float*)d_in[0];
    const float* hB     = (const float*)d_in[1];
    const float* Wself  = (const float*)d_in[2];
    const float* bself  = (const float*)d_in[3];
    const float* Wq     = (const float*)d_in[4];
    const float* bq     = (const float*)d_in[5];
    const float* Wk     = (const float*)d_in[6];
    const float* bk     = (const float*)d_in[7];
    const float* Wal    = (const float*)d_in[8];
    const float* bal    = (const float*)d_in[9];
    const float* War    = (const float*)d_in[10];
    const float* bar    = (const float*)d_in[11];
    const float* Wsrc   = (const float*)d_in[12];
    const float* bsrc   = (const float*)d_in[13];
    const float* Wdst   = (const float*)d_in[14];
    const float* bdst   = (const float*)d_in[15];
    const float* attn_v = (const float*)d_in[16];
    const float* gbias  = (const float*)d_in[17];
    const int* eab_src  = (const int*)d_in[18];
    const int* eab_dst  = (const int*)d_in[19];
    const int* eba_src  = (const int*)d_in[20];
    const int* eba_dst  = (const int*)d_in[21];
    float* out = (float*)d_out;
    char* ws = (char*)d_ws;

    // ---- workspace layout (256B-aligned blocks)
    const size_t SZ_BUF = (size_t)NNODES * 768 * sizeof(unsigned short);  // 76.8 MB
    const size_t SZ_H   = (size_t)NNODES * 256 * sizeof(unsigned short);  // 25.6 MB
    size_t off = 0;
    auto alloc = [&](size_t bytes) { void* p = ws + off; off = (off + bytes + 255) & ~(size_t)255; return p; };
    unsigned short* bufA = (unsigned short*)alloc(SZ_BUF);  // [z0 | ftS_ab | ftD_ba]
    unsigned short* bufB = (unsigned short*)alloc(SZ_BUF);  // [z1 | ftS_ba | ftD_ab]
    unsigned short* hAb  = (unsigned short*)alloc(SZ_H);
    unsigned short* hBb  = (unsigned short*)alloc(SZ_H);
    unsigned short* Wt   = (unsigned short*)alloc(2 * 768 * 256 * sizeof(unsigned short));
    float* biasF   = (float*)alloc(2 * 768 * sizeof(float));
    float* aux     = (float*)alloc((size_t)8 * NNODES * sizeof(float));   // ps|pd|hl|hr
    int* counts    = (int*)alloc(NBINS * sizeof(int));
    int* row_start = (int*)alloc(NBINS * sizeof(int));
    int* cursor    = (int*)alloc(NBINS * sizeof(int));
    int* bsum      = (int*)alloc(512 * sizeof(int));
    int* sorted_src= (int*)alloc(2 * (size_t)NEDGES * sizeof(int));
    float* u_l     = (float*)alloc(2 * 256 * sizeof(float));
    float* u_r     = (float*)alloc(2 * 256 * sizeof(float));
    float* c_l     = (float*)alloc(2 * sizeof(float));
    float* c_r     = (float*)alloc(2 * sizeof(float));

    hipMemsetAsync(counts, 0, NBINS * sizeof(int), stream);
    hipMemsetAsync(aux, 0, (size_t)8 * NNODES * sizeof(float), stream);

    // ---- bf16 conversions + merged weight pack / uv precompute
    const int HN = NNODES * 256;
    conv_bf16_2<<<(2 * HN / 4 + 255) / 256, 256, 0, stream>>>(hA, hB, hAb, hBb, HN);
    prep_all<<<2 + 2 * 768, 256, 0, stream>>>(Wself, Wsrc, Wdst, bself, bsrc, bdst,
                                              Wq, bq, Wk, bk, Wal, bal, War, bar,
                                              Wt, biasF, u_l, u_r, c_l, c_r);

    // ---- counting sort of edges by dst (bins: [0,N)=ab, [N,2N)=ba)
    const int e2blocks = (2 * NEDGES + 255) / 256;
    hist2<<<e2blocks, 256, 0, stream>>>(eab_dst, eba_dst, counts);
    const int sblocks = (NBINS + 255) / 256;
    scan1<<<sblocks, 256, 0, stream>>>(counts, row_start, bsum, NBINS);
    scan2<<<1, 512, 0, stream>>>(bsum, sblocks);
    scan3<<<sblocks, 256, 0, stream>>>(counts, row_start, bsum, cursor, NBINS);
    scatter2<<<e2blocks, 256, 0, stream>>>(eab_src, eab_dst, eba_src, eba_dst, cursor, sorted_src);

    // ---- 1-wave barrier-free MFMA GEMM (both types, one dispatch) + aux node-dots
    gemm_mfma<<<NWG_GEMM, 64, 0, stream>>>(hAb, hBb, Wt, biasF, attn_v, u_l, u_r,
                                           bufA, bufB, aux, NNODES);

    // ---- fully fused GAT + node attention + combine
    gat_fused<<<(2 * NNODES + 15) / 16, 256, 0, stream>>>(bufA, bufB, sorted_src, row_start,
                                                          counts, attn_v, gbias, u_l,
                                                          c_l, c_r, aux, out);
}

// Round 9
// 282.091 us; speedup vs baseline: 1.0451x; 1.0451x over previous
//
#include <hip/hip_runtime.h>
#include <math.h>

#define NNODES 50000
#define NEDGES 262144
#define NEG_SLOPE 0.2f
#define NBINS (2 * NNODES)
#define NXP 391                    // ceil(50000/128)
#define NWG_GEMM (2 * NXP * 6)     // 4692

typedef __attribute__((ext_vector_type(8))) short short8;   // 8 x bf16 (16B)
typedef __attribute__((ext_vector_type(4))) float f32x4;    // MFMA acc
typedef __attribute__((ext_vector_type(2))) float f32x2;
typedef __attribute__((ext_vector_type(4))) unsigned short u16x4;

// aux layout (floats): [0,2N) ps per rel (rel*N+src) ; [2N,4N) pd per rel ;
//                      [4N,6N) hl per type (t*N+node) ; [6N,8N) hr per type
#define AUX_PS 0
#define AUX_PD (2 * NNODES)
#define AUX_HL (4 * NNODES)
#define AUX_HR (6 * NNODES)

// ---------- helpers ----------
__device__ __forceinline__ float elu_f(float x) { return x > 0.f ? x : (__expf(x) - 1.f); }
__device__ __forceinline__ float bf2f(unsigned short u) {
    return __uint_as_float(((unsigned)u) << 16);
}
__device__ __forceinline__ f32x2 bfp2f(unsigned p) {   // 2 packed bf16 -> 2 f32
    f32x2 r;
    r.x = __uint_as_float(p << 16);
    r.y = __uint_as_float(p & 0xffff0000u);
    return r;
}
__device__ __forceinline__ unsigned short f2bf(float f) {
    unsigned u = __float_as_uint(f);
    unsigned r = (u + 0x7fffu + ((u >> 16) & 1u)) >> 16;   // RNE
    return (unsigned short)r;
}

// ---------- merged: precompute u_l/u_r/c_l/c_r (blocks 0-1) + weight pack (blocks 2..1537)
__global__ __launch_bounds__(256) void prep_all(
    const float* __restrict__ Wself, const float* __restrict__ Wsrc, const float* __restrict__ Wdst,
    const float* __restrict__ bself, const float* __restrict__ bsrc, const float* __restrict__ bdst,
    const float* __restrict__ Wq, const float* __restrict__ bq,
    const float* __restrict__ Wk, const float* __restrict__ bk,
    const float* __restrict__ Wal, const float* __restrict__ bal,
    const float* __restrict__ War, const float* __restrict__ bar,
    unsigned short* __restrict__ Wt, float* __restrict__ biasF,
    float* __restrict__ u_l, float* __restrict__ u_r,
    float* __restrict__ c_l, float* __restrict__ c_r) {
    if (blockIdx.x < 2) {
        int t = blockIdx.x;
        int d = threadIdx.x;
        float sl = 0.f, sr = 0.f;
        for (int j = 0; j < 64; ++j) {
            sl += Wk[((size_t)t * 256 + d) * 64 + j] * Wal[t * 64 + j];
            sr += Wq[((size_t)t * 256 + d) * 64 + j] * War[t * 64 + j];
        }
        u_l[t * 256 + d] = sl;
        u_r[t * 256 + d] = sr;
        if (d == 0) {
            float cl = bal[t], cr = bar[t];
            for (int j = 0; j < 64; ++j) {
                cl += bk[t * 64 + j] * Wal[t * 64 + j];
                cr += bq[t * 64 + j] * War[t * 64 + j];
            }
            c_l[t] = cl; c_r[t] = cr;
        }
        return;
    }
    int r = blockIdx.x - 2;        // 0..1535 = t*768 + n
    int t = r / 768;
    int n = r % 768;
    int seg = n >> 8;
    int nn = n & 255;
    const float* W; const float* bv; int ti;
    if (seg == 0)      { W = Wself; bv = bself; ti = t; }
    else if (seg == 1) { W = Wsrc;  bv = bsrc;  ti = t; }
    else               { W = Wdst;  bv = bdst;  ti = 1 - t; }
    int k = threadIdx.x;
    float val = W[(size_t)ti * 65536 + (size_t)k * 256 + nn];
    Wt[(size_t)r * 256 + k] = f2bf(val);
    if (k == 0) biasF[r] = bv[ti * 256 + nn];
}

// ---------- counting sort (both relations per dispatch) ----------
__global__ __launch_bounds__(256) void hist2(const int* __restrict__ dab,
                                             const int* __restrict__ dba,
                                             int* __restrict__ counts) {
    int e = blockIdx.x * 256 + threadIdx.x;
    if (e < NEDGES) atomicAdd(&counts[dab[e]], 1);
    else if (e < 2 * NEDGES) atomicAdd(&counts[NNODES + dba[e - NEDGES]], 1);
}

__global__ __launch_bounds__(256) void scan1(const int* __restrict__ counts,
                                             int* __restrict__ incl,
                                             int* __restrict__ bsum, int n) {
    __shared__ int s[256];
    int i = blockIdx.x * 256 + threadIdx.x;
    int t = threadIdx.x;
    s[t] = (i < n) ? counts[i] : 0;
    __syncthreads();
#pragma unroll
    for (int off = 1; off < 256; off <<= 1) {
        int x = (t >= off) ? s[t - off] : 0;
        __syncthreads();
        s[t] += x;
        __syncthreads();
    }
    if (i < n) incl[i] = s[t];
    if (t == 255) bsum[blockIdx.x] = s[255];
}

__global__ __launch_bounds__(512) void scan2(int* __restrict__ bsum, int nb) {
    __shared__ int s[512];
    int t = threadIdx.x;
    s[t] = (t < nb) ? bsum[t] : 0;
    __syncthreads();
#pragma unroll
    for (int off = 1; off < 512; off <<= 1) {
        int x = (t >= off) ? s[t - off] : 0;
        __syncthreads();
        s[t] += x;
        __syncthreads();
    }
    if (t < nb) bsum[t] = s[t];
}

__global__ __launch_bounds__(256) void scan3(const int* __restrict__ counts,
                                             int* __restrict__ incl_to_excl,
                                             const int* __restrict__ bsum,
                                             int* __restrict__ cursor, int n) {
    int i = blockIdx.x * 256 + threadIdx.x;
    if (i >= n) return;
    int base = (blockIdx.x > 0) ? bsum[blockIdx.x - 1] : 0;
    int st = base + incl_to_excl[i] - counts[i];
    incl_to_excl[i] = st;
    cursor[i] = st;
}

__global__ __launch_bounds__(256) void scatter2(const int* __restrict__ sab,
                                                const int* __restrict__ dab,
                                                const int* __restrict__ sba,
                                                const int* __restrict__ dba,
                                                int* __restrict__ cursor,
                                                int* __restrict__ sorted_src) {
    int e = blockIdx.x * 256 + threadIdx.x;
    if (e < NEDGES) {
        int pos = atomicAdd(&cursor[dab[e]], 1);
        sorted_src[pos] = sab[e];
    } else if (e < 2 * NEDGES) {
        int k = e - NEDGES;
        int pos = atomicAdd(&cursor[NNODES + dba[k]], 1);
        sorted_src[pos] = sba[k];
    }
}

// ---------- fused bf16 MFMA GEMM (both types, one dispatch), counted-vmcnt pipeline.
// A is read DIRECTLY from f32 inputs: reg-staged (load f32 one tile ahead -> cvt ->
// ds_write) -- the f32->bf16 conversion pass is fused away. B via global_load_lds.
// vmcnt FIFO per tile: A = 4 flat loads, B = 2 gload_lds.
__global__ __launch_bounds__(256) void gemm_mfma(
    const float* __restrict__ hA,
    const float* __restrict__ hB,
    const unsigned short* __restrict__ Wt,
    const float* __restrict__ biasF,
    const float* __restrict__ attn_v,
    const float* __restrict__ u_l,
    const float* __restrict__ u_r,
    unsigned short* __restrict__ bufA,
    unsigned short* __restrict__ bufB,
    float* __restrict__ aux,
    int M)
{
    __shared__ unsigned short lds[16384];   // 32KB: A bufs @0,4096; B bufs @8192,12288 (elems)
    const int tid = threadIdx.x;
    const int lane = tid & 63;
    const int w = tid >> 6;
    const int wm = w >> 1, wn = w & 1;

    // bijective XCD swizzle (m204)
    const int nwg = NWG_GEMM;
    const int q = nwg / 8, r = nwg % 8;
    int orig = blockIdx.x;
    int xcd = orig % 8, idx = orig / 8;
    int wgid = (xcd < r) ? (xcd * (q + 1) + idx) : (r * (q + 1) + (xcd - r) * q + idx);
    int t   = wgid / (NXP * 6);
    int rem = wgid % (NXP * 6);
    int xp  = rem / 6;
    int yc  = rem % 6;

    const int row0 = xp * 128;
    const int col0 = yc * 128;
    const float* Afin = t ? hB : hA;
    const unsigned short* Wtt = Wt + (size_t)t * 768 * 256;
    const float* bias = biasF + t * 768;
    unsigned short* Cout = t ? bufB : bufA;

    f32x4 acc[4][4] = {};

    // staging addresses: chunk qq = rr*256+tid; row=qq>>2, slot=qq&3,
    // k-chunk kc = slot ^ ((row>>1)&3) (both-sides swizzle, G21)
    const float* gAf[2];
    const unsigned short* gB[2];
#pragma unroll
    for (int rr = 0; rr < 2; ++rr) {
        int qq = rr * 256 + tid;
        int row = qq >> 2;
        int kc = (qq & 3) ^ ((row >> 1) & 3);
        int ga = min(row0 + row, M - 1);
        gAf[rr] = Afin + (size_t)ga * 256 + kc * 8;
        gB[rr] = Wtt + (size_t)(col0 + row) * 256 + kc * 8;
    }

    float4 aR[2][4];   // two A-tiles in flight (reg staging), parity-indexed

#define ISSUE_A(p, kt)                                                           \
    {                                                                            \
        _Pragma("unroll")                                                        \
        for (int rr = 0; rr < 2; ++rr) {                                         \
            aR[p][2 * rr]     = *reinterpret_cast<const float4*>(gAf[rr] + (kt));     \
            aR[p][2 * rr + 1] = *reinterpret_cast<const float4*>(gAf[rr] + (kt) + 4); \
        }                                                                        \
    }

#define WRITE_A(p)                                                               \
    {                                                                            \
        unsigned short* Ad = lds + (p) * 4096;                                   \
        _Pragma("unroll")                                                        \
        for (int rr = 0; rr < 2; ++rr) {                                         \
            float4 lo = aR[p][2 * rr], hi = aR[p][2 * rr + 1];                   \
            short8 v;                                                            \
            v[0] = (short)f2bf(lo.x); v[1] = (short)f2bf(lo.y);                  \
            v[2] = (short)f2bf(lo.z); v[3] = (short)f2bf(lo.w);                  \
            v[4] = (short)f2bf(hi.x); v[5] = (short)f2bf(hi.y);                  \
            v[6] = (short)f2bf(hi.z); v[7] = (short)f2bf(hi.w);                  \
            *reinterpret_cast<short8*>(&Ad[(rr * 256 + tid) << 3]) = v;          \
        }                                                                        \
    }

#define STAGE_B(buf, kt)                                                                 \
    {                                                                                    \
        unsigned short* Bd = lds + 8192 + (buf) * 4096;                                  \
        _Pragma("unroll")                                                                \
        for (int rr = 0; rr < 2; ++rr) {                                                 \
            __builtin_amdgcn_global_load_lds(                                            \
                (const __attribute__((address_space(1))) unsigned int*)(gB[rr] + (kt)),  \
                (__attribute__((address_space(3))) unsigned int*)(Bd + ((rr * 256 + w * 64) << 3)), \
                16, 0, 0);                                                               \
        }                                                                                \
    }

    // prologue: FIFO [A0(4), B0(2), A1(4), B1(2)]
    ISSUE_A(0, 0);
    STAGE_B(0, 0);
    ISSUE_A(1, 32);
    STAGE_B(1, 32);
    asm volatile("s_waitcnt vmcnt(6)" ::: "memory");   // A0+B0 done; A1,B1 in flight
    WRITE_A(0);
    asm volatile("s_waitcnt lgkmcnt(0)" ::: "memory");

#pragma unroll
    for (int it = 0; it < 8; ++it) {
        const int cur = it & 1;
        // top: ensure B(it) landed (A(it) was ds_written + lgkm'd last iter)
        if (it < 7) { asm volatile("s_waitcnt vmcnt(6)" ::: "memory"); }
        else        { asm volatile("s_waitcnt vmcnt(0)" ::: "memory"); }
        __builtin_amdgcn_s_barrier();
        __builtin_amdgcn_sched_barrier(0);

        if (it < 6) ISSUE_A(cur, (it + 2) * 32);   // A(it+2) -> regs, hides under MFMA

        const unsigned short* As = lds + cur * 4096;
        const unsigned short* Bs = lds + 8192 + cur * 4096;
        short8 a[4], b[4];
#pragma unroll
        for (int i = 0; i < 4; ++i) {
            int ar = wm * 64 + i * 16 + (lane & 15);
            a[i] = *reinterpret_cast<const short8*>(
                &As[ar * 32 + (((lane >> 4) ^ ((ar >> 1) & 3)) << 3)]);
            int br = wn * 64 + i * 16 + (lane & 15);
            b[i] = *reinterpret_cast<const short8*>(
                &Bs[br * 32 + (((lane >> 4) ^ ((br >> 1) & 3)) << 3)]);
        }
#pragma unroll
        for (int i = 0; i < 4; ++i)
#pragma unroll
            for (int j = 0; j < 4; ++j)
                acc[i][j] = __builtin_amdgcn_mfma_f32_16x16x32_bf16(a[i], b[j], acc[i][j], 0, 0, 0);

        asm volatile("s_waitcnt lgkmcnt(0)" ::: "memory");
        __builtin_amdgcn_sched_barrier(0);
        __builtin_amdgcn_s_barrier();               // buf cur free for tile it+2

        if (it < 7) {
            // wait A(it+1) regs (leave A(it+2)+B(it+2)-to-be in flight)
            if (it < 6) { asm volatile("s_waitcnt vmcnt(6)" ::: "memory"); }
            else        { asm volatile("s_waitcnt vmcnt(2)" ::: "memory"); }
            __builtin_amdgcn_sched_barrier(0);
            WRITE_A(cur ^ 1);                       // tile it+1 A -> buf cur^1
            if (it < 6) STAGE_B(cur, (it + 2) * 32);// tile it+2 B -> buf cur
            asm volatile("s_waitcnt lgkmcnt(0)" ::: "memory");
        }
    }
#undef ISSUE_A
#undef WRITE_A
#undef STAGE_B

    // ---- epilogue: acc (+bias) -> LDS [128][128] bf16 with per-row col-group XOR
#pragma unroll
    for (int j = 0; j < 4; ++j) {
        int colg = wn * 4 + j;                 // 16-elem col group
        int ci = lane & 15;
        float bv = bias[col0 + colg * 16 + ci];
#pragma unroll
        for (int i = 0; i < 4; ++i) {
            int rowb = wm * 64 + i * 16 + ((lane >> 4) << 2);
#pragma unroll
            for (int v = 0; v < 4; ++v) {
                int row = rowb + v;
                int g2 = colg ^ ((row >> 2) & 3);
                lds[row * 128 + g2 * 16 + ci] = f2bf(acc[i][j][v] + bv);
            }
        }
    }
    __syncthreads();

    // which node-dot(s) this column-panel contributes to:
    const int seg = yc >> 1;                   // 0:z, 1:ftS, 2:ftD
    const float* avp1; float* axp1;
    const float* avp2 = nullptr; float* axp2 = nullptr;
    if (seg == 0) {
        avp1 = u_l + t * 256;            axp1 = aux + AUX_HL + (size_t)t * NNODES;
        avp2 = u_r + t * 256;            axp2 = aux + AUX_HR + (size_t)t * NNODES;
    } else if (seg == 1) {
        avp1 = attn_v + t * 256;         axp1 = aux + AUX_PS + (size_t)t * NNODES;
    } else {
        avp1 = attn_v + (1 - t) * 256;   axp1 = aux + AUX_PD + (size_t)(1 - t) * NNODES;
    }

#pragma unroll
    for (int p = 0; p < 8; ++p) {
        int idx = p * 256 + tid;
        int row = idx >> 4;
        int ch = idx & 15;                      // 8-elem (16B) chunk
        int g2 = (ch >> 1) ^ ((row >> 2) & 3);
        int grow = row0 + row;
        bool ok = grow < M;
        short8 val = *reinterpret_cast<const short8*>(&lds[row * 128 + g2 * 16 + ((ch & 1) << 3)]);
        if (ok)
            *reinterpret_cast<short8*>(&Cout[(size_t)grow * 768 + col0 + ch * 8]) = val;
        // partial node-dot over this chunk's 8 cols (2 partials/node -> deterministic)
        int colb = (yc & 1) * 128 + ch * 8;
        float4 w0v = *reinterpret_cast<const float4*>(&avp1[colb]);
        float4 w1v = *reinterpret_cast<const float4*>(&avp1[colb + 4]);
        float p1 = w0v.x * bf2f((unsigned short)val[0]) + w0v.y * bf2f((unsigned short)val[1])
                 + w0v.z * bf2f((unsigned short)val[2]) + w0v.w * bf2f((unsigned short)val[3])
                 + w1v.x * bf2f((unsigned short)val[4]) + w1v.y * bf2f((unsigned short)val[5])
                 + w1v.z * bf2f((unsigned short)val[6]) + w1v.w * bf2f((unsigned short)val[7]);
        p1 += __shfl_xor(p1, 1);
        p1 += __shfl_xor(p1, 2);
        p1 += __shfl_xor(p1, 4);
        p1 += __shfl_xor(p1, 8);
        if ((tid & 15) == 0 && ok) atomicAdd(&axp1[grow], p1);
        if (avp2) {
            float4 y0 = *reinterpret_cast<const float4*>(&avp2[colb]);
            float4 y1 = *reinterpret_cast<const float4*>(&avp2[colb + 4]);
            float p2 = y0.x * bf2f((unsigned short)val[0]) + y0.y * bf2f((unsigned short)val[1])
                     + y0.z * bf2f((unsigned short)val[2]) + y0.w * bf2f((unsigned short)val[3])
                     + y1.x * bf2f((unsigned short)val[4]) + y1.y * bf2f((unsigned short)val[5])
                     + y1.z * bf2f((unsigned short)val[6]) + y1.w * bf2f((unsigned short)val[7]);
            p2 += __shfl_xor(p2, 1);
            p2 += __shfl_xor(p2, 2);
            p2 += __shfl_xor(p2, 4);
            p2 += __shfl_xor(p2, 8);
            if ((tid & 15) == 0 && ok) atomicAdd(&axp2[grow], p2);
        }
    }
}

// ---------- fully fused per-dst GATv2 + node attention + combine
// 16 lanes/dst, 4 dsts/wave. lrelu factorization: logit = 0.6(ps+pd) + 0.4*sum(av*|fs+fd|)
// ps/pd/hl/hr precomputed in gemm epilogue (aux). No-max softmax (logits ~N(0,1)).
__global__ __launch_bounds__(256) void gat_fused(
    const unsigned short* __restrict__ bufA, const unsigned short* __restrict__ bufB,
    const int* __restrict__ sorted_src, const int* __restrict__ row_start,
    const int* __restrict__ counts,
    const float* __restrict__ attn_v, const float* __restrict__ gbias,
    const float* __restrict__ u_l,
    const float* __restrict__ c_l, const float* __restrict__ c_r,
    const float* __restrict__ aux,
    float* __restrict__ out)
{
    const int tid = threadIdx.x;
    const int l = tid & 15;            // lane in 16-group
    const int gBase = tid & 48;        // group base lane within wave
    const int nd = blockIdx.x * 16 + (tid >> 4);
    if (nd >= 2 * NNODES) return;
    const int rel = nd >= NNODES;      // 0: ab (dst type B), 1: ba (dst type A)
    const int d = nd - rel * NNODES;
    const int td = rel ? 0 : 1;        // dst node type

    const unsigned short* zbuf = td ? bufB : bufA;
    const unsigned short* ftS = (rel ? bufB : bufA) + 256;
    const unsigned short* ftD = zbuf + 512;
    const float clv = c_l[td], crv = c_r[td];

    // per-lane dims [l*16, l*16+16) as f32x2 pairs
    f32x2 fd2[8], av2[8];
    {
        const unsigned short* fdp = &ftD[(size_t)d * 768 + l * 16];
        uint4 d0 = *reinterpret_cast<const uint4*>(fdp);
        uint4 d1 = *reinterpret_cast<const uint4*>(fdp + 8);
        fd2[0] = bfp2f(d0.x); fd2[1] = bfp2f(d0.y); fd2[2] = bfp2f(d0.z); fd2[3] = bfp2f(d0.w);
        fd2[4] = bfp2f(d1.x); fd2[5] = bfp2f(d1.y); fd2[6] = bfp2f(d1.z); fd2[7] = bfp2f(d1.w);
        const float* avp = attn_v + rel * 256 + l * 16;
#pragma unroll
        for (int e = 0; e < 4; ++e) {
            float4 a = *reinterpret_cast<const float4*>(&avp[e * 4]);
            av2[2 * e].x = a.x; av2[2 * e].y = a.y;
            av2[2 * e + 1].x = a.z; av2[2 * e + 1].y = a.w;
        }
    }

    const float pd6 = 0.6f * aux[AUX_PD + (size_t)rel * NNODES + d];
    const float hlv = aux[AUX_HL + (size_t)td * NNODES + d] + clv;
    const float hrv = aux[AUX_HR + (size_t)td * NNODES + d] + crv;
    const float a0 = elu_f(hlv + hrv);           // att_self (pre-softmax)
    const float* psb = aux + AUX_PS + (size_t)rel * NNODES;

    const int p0  = row_start[nd];
    const int cnt = counts[nd];
    float den = 0.f;
    f32x2 acc2[8];
#pragma unroll
    for (int e = 0; e < 8; ++e) { acc2[e].x = 0.f; acc2[e].y = 0.f; }

    for (int base = 0; base < cnt; base += 16) {
        int nloc = min(16, cnt - base);
        int sv = 0; float psl = 0.f;
        if (base + l < cnt) { sv = sorted_src[p0 + base + l]; psl = psb[sv]; }
        int j = 0;
        for (; j + 2 <= nloc; j += 2) {
            int s0 = __shfl(sv, gBase + j);
            int s1 = __shfl(sv, gBase + j + 1);
            float q0 = __shfl(psl, gBase + j);
            float q1 = __shfl(psl, gBase + j + 1);
            const unsigned short* rp0 = &ftS[(size_t)s0 * 768 + l * 16];
            const unsigned short* rp1 = &ftS[(size_t)s1 * 768 + l * 16];
            uint4 A0 = *reinterpret_cast<const uint4*>(rp0);
            uint4 A1 = *reinterpret_cast<const uint4*>(rp0 + 8);
            uint4 B0 = *reinterpret_cast<const uint4*>(rp1);
            uint4 B1 = *reinterpret_cast<const uint4*>(rp1 + 8);
            f32x2 fa2[8], fb2[8];
            fa2[0] = bfp2f(A0.x); fa2[1] = bfp2f(A0.y); fa2[2] = bfp2f(A0.z); fa2[3] = bfp2f(A0.w);
            fa2[4] = bfp2f(A1.x); fa2[5] = bfp2f(A1.y); fa2[6] = bfp2f(A1.z); fa2[7] = bfp2f(A1.w);
            fb2[0] = bfp2f(B0.x); fb2[1] = bfp2f(B0.y); fb2[2] = bfp2f(B0.z); fb2[3] = bfp2f(B0.w);
            fb2[4] = bfp2f(B1.x); fb2[5] = bfp2f(B1.y); fb2[6] = bfp2f(B1.z); fb2[7] = bfp2f(B1.w);
            float Sa = 0.f, Sb = 0.f;
#pragma unroll
            for (int e = 0; e < 8; ++e) {
                f32x2 xa = fa2[e] + fd2[e];
                f32x2 xb = fb2[e] + fd2[e];
                Sa += av2[e].x * fabsf(xa.x);
                Sa += av2[e].y * fabsf(xa.y);
                Sb += av2[e].x * fabsf(xb.x);
                Sb += av2[e].y * fabsf(xb.y);
            }
            Sa += __shfl_xor(Sa, 1); Sb += __shfl_xor(Sb, 1);
            Sa += __shfl_xor(Sa, 2); Sb += __shfl_xor(Sb, 2);
            Sa += __shfl_xor(Sa, 4); Sb += __shfl_xor(Sb, 4);
            Sa += __shfl_xor(Sa, 8); Sb += __shfl_xor(Sb, 8);
            float wa = __expf(fmaf(0.6f, q0, pd6) + 0.4f * Sa);
            float wb = __expf(fmaf(0.6f, q1, pd6) + 0.4f * Sb);
            den += wa + wb;
#pragma unroll
            for (int e = 0; e < 8; ++e) acc2[e] += wa * fa2[e] + wb * fb2[e];
        }
        if (j < nloc) {
            int s0 = __shfl(sv, gBase + j);
            float q0 = __shfl(psl, gBase + j);
            const unsigned short* rp0 = &ftS[(size_t)s0 * 768 + l * 16];
            uint4 A0 = *reinterpret_cast<const uint4*>(rp0);
            uint4 A1 = *reinterpret_cast<const uint4*>(rp0 + 8);
            f32x2 fa2[8];
            fa2[0] = bfp2f(A0.x); fa2[1] = bfp2f(A0.y); fa2[2] = bfp2f(A0.z); fa2[3] = bfp2f(A0.w);
            fa2[4] = bfp2f(A1.x); fa2[5] = bfp2f(A1.y); fa2[6] = bfp2f(A1.z); fa2[7] = bfp2f(A1.w);
            float Sa = 0.f;
#pragma unroll
            for (int e = 0; e < 8; ++e) {
                f32x2 xa = fa2[e] + fd2[e];
                Sa += av2[e].x * fabsf(xa.x);
                Sa += av2[e].y * fabsf(xa.y);
            }
            Sa += __shfl_xor(Sa, 1);
            Sa += __shfl_xor(Sa, 2);
            Sa += __shfl_xor(Sa, 4);
            Sa += __shfl_xor(Sa, 8);
            float wa = __expf(fmaf(0.6f, q0, pd6) + 0.4f * Sa);
            den += wa;
#pragma unroll
            for (int e = 0; e < 8; ++e) acc2[e] += wa * fa2[e];
        }
    }

    // ---- finalize rst row: v = acc/den + gbias
    float inv = den > 0.f ? 1.f / den : 1.f;
    const float* gb = gbias + rel * 256 + l * 16;
    const float* ulp = u_l + td * 256 + l * 16;
    f32x2 v2[8];
    float dotv = 0.f;
#pragma unroll
    for (int e = 0; e < 4; ++e) {
        float4 g = *reinterpret_cast<const float4*>(&gb[e * 4]);
        float4 u = *reinterpret_cast<const float4*>(&ulp[e * 4]);
        v2[2 * e].x     = acc2[2 * e].x     * inv + g.x;
        v2[2 * e].y     = acc2[2 * e].y     * inv + g.y;
        v2[2 * e + 1].x = acc2[2 * e + 1].x * inv + g.z;
        v2[2 * e + 1].y = acc2[2 * e + 1].y * inv + g.w;
        dotv += v2[2 * e].x * u.x + v2[2 * e].y * u.y
              + v2[2 * e + 1].x * u.z + v2[2 * e + 1].y * u.w;
    }
    dotv += __shfl_xor(dotv, 1);
    dotv += __shfl_xor(dotv, 2);
    dotv += __shfl_xor(dotv, 4);
    dotv += __shfl_xor(dotv, 8);
    const float ea = elu_f(dotv + clv + hrv);

    // ---- 2-way softmax combine + final elu, write output row
    float mx = fmaxf(a0, ea);
    float e0 = __expf(a0 - mx), e1 = __expf(ea - mx);
    float is = 1.f / (e0 + e1);
    float w0 = e0 * is, w1 = e1 * is;

    const unsigned short* zrow = zbuf + (size_t)d * 768 + l * 16;
    uint4 z0 = *reinterpret_cast<const uint4*>(zrow);
    uint4 z1 = *reinterpret_cast<const uint4*>(zrow + 8);
    f32x2 zf2[8];
    zf2[0] = bfp2f(z0.x); zf2[1] = bfp2f(z0.y); zf2[2] = bfp2f(z0.z); zf2[3] = bfp2f(z0.w);
    zf2[4] = bfp2f(z1.x); zf2[5] = bfp2f(z1.y); zf2[6] = bfp2f(z1.z); zf2[7] = bfp2f(z1.w);

    float* orow = out + ((size_t)(1 - rel) * NNODES + d) * 256 + l * 16;
#pragma unroll
    for (int e = 0; e < 4; ++e) {
        float4 o;
        o.x = elu_f(w0 * zf2[2 * e].x     + w1 * v2[2 * e].x);
        o.y = elu_f(w0 * zf2[2 * e].y     + w1 * v2[2 * e].y);
        o.z = elu_f(w0 * zf2[2 * e + 1].x + w1 * v2[2 * e + 1].x);
        o.w = elu_f(w0 * zf2[2 * e + 1].y + w1 * v2[2 * e + 1].y);
        *reinterpret_cast<float4*>(&orow[e * 4]) = o;
    }
}

extern "C" void kernel_launch(void* const* d_in, const int* in_sizes, int n_in,
                              void* d_out, int out_size, void* d_ws, size_t ws_size,
                              hipStream_t stream) {
    const float* hA     = (const float*)d_in[0];
    const float* hB     = (const float*)d_in[1];
    const float* Wself  = (const float*)d_in[2];
    const float* bself  = (const float*)d_in[3];
    const float* Wq     = (const float*)d_in[4];
    const float* bq     = (const float*)d_in[5];
    const float* Wk     = (const float*)d_in[6];
    const float* bk     = (const float*)d_in[7];
    const float* Wal    = (const float*)d_in[8];
    const float* bal    = (const float*)d_in[9];
    const float* War    = (const float*)d_in[10];
    const float* bar    = (const float*)d_in[11];
    const float* Wsrc   = (const float*)d_in[12];
    const float* bsrc   = (const float*)d_in[13];
    const float* Wdst   = (const float*)d_in[14];
    const float* bdst   = (const float*)d_in[15];
    const float* attn_v = (const float*)d_in[16];
    const float* gbias  = (const float*)d_in[17];
    const int* eab_src  = (const int*)d_in[18];
    const int* eab_dst  = (const int*)d_in[19];
    const int* eba_src  = (const int*)d_in[20];
    const int* eba_dst  = (const int*)d_in[21];
    float* out = (float*)d_out;
    char* ws = (char*)d_ws;

    // ---- workspace layout (256B-aligned blocks)
    const size_t SZ_BUF = (size_t)NNODES * 768 * sizeof(unsigned short);  // 76.8 MB
    size_t off = 0;
    auto alloc = [&](size_t bytes) { void* p = ws + off; off = (off + bytes + 255) & ~(size_t)255; return p; };
    unsigned short* bufA = (unsigned short*)alloc(SZ_BUF);  // [z0 | ftS_ab | ftD_ba]
    unsigned short* bufB = (unsigned short*)alloc(SZ_BUF);  // [z1 | ftS_ba | ftD_ab]
    unsigned short* Wt   = (unsigned short*)alloc(2 * 768 * 256 * sizeof(unsigned short));
    float* biasF   = (float*)alloc(2 * 768 * sizeof(float));
    float* aux     = (float*)alloc((size_t)8 * NNODES * sizeof(float));   // ps|pd|hl|hr
    int* counts    = (int*)alloc(NBINS * sizeof(int));
    int* row_start = (int*)alloc(NBINS * sizeof(int));
    int* cursor    = (int*)alloc(NBINS * sizeof(int));
    int* bsum      = (int*)alloc(512 * sizeof(int));
    int* sorted_src= (int*)alloc(2 * (size_t)NEDGES * sizeof(int));
    float* u_l     = (float*)alloc(2 * 256 * sizeof(float));
    float* u_r     = (float*)alloc(2 * 256 * sizeof(float));
    float* c_l     = (float*)alloc(2 * sizeof(float));
    float* c_r     = (float*)alloc(2 * sizeof(float));

    hipMemsetAsync(counts, 0, NBINS * sizeof(int), stream);
    hipMemsetAsync(aux, 0, (size_t)8 * NNODES * sizeof(float), stream);

    // ---- merged weight pack / uv precompute (no separate conv pass anymore)
    prep_all<<<2 + 2 * 768, 256, 0, stream>>>(Wself, Wsrc, Wdst, bself, bsrc, bdst,
                                              Wq, bq, Wk, bk, Wal, bal, War, bar,
                                              Wt, biasF, u_l, u_r, c_l, c_r);

    // ---- counting sort of edges by dst (bins: [0,N)=ab, [N,2N)=ba)
    const int e2blocks = (2 * NEDGES + 255) / 256;
    hist2<<<e2blocks, 256, 0, stream>>>(eab_dst, eba_dst, counts);
    const int sblocks = (NBINS + 255) / 256;
    scan1<<<sblocks, 256, 0, stream>>>(counts, row_start, bsum, NBINS);
    scan2<<<1, 512, 0, stream>>>(bsum, sblocks);
    scan3<<<sblocks, 256, 0, stream>>>(counts, row_start, bsum, cursor, NBINS);
    scatter2<<<e2blocks, 256, 0, stream>>>(eab_src, eab_dst, eba_src, eba_dst, cursor, sorted_src);

    // ---- fused MFMA GEMM (both types, one dispatch; A converted in-kernel) + aux node-dots
    gemm_mfma<<<NWG_GEMM, 256, 0, stream>>>(hA, hB, Wt, biasF, attn_v, u_l, u_r,
                                            bufA, bufB, aux, NNODES);

    // ---- fully fused GAT + node attention + combine
    gat_fused<<<(2 * NNODES + 15) / 16, 256, 0, stream>>>(bufA, bufB, sorted_src, row_start,
                                                          counts, attn_v, gbias, u_l,
                                                          c_l, c_r, aux, out);
}

// Round 10
// 272.608 us; speedup vs baseline: 1.0815x; 1.0348x over previous
//
#include <hip/hip_runtime.h>
#include <math.h>

#define NNODES 50000
#define NEDGES 262144
#define NEG_SLOPE 0.2f
#define NBINS (2 * NNODES)
#define NXP 391                    // ceil(50000/128)
#define NWG_GEMM (2 * NXP * 6)     // 4692

typedef __attribute__((ext_vector_type(8))) short short8;   // 8 x bf16 (16B)
typedef __attribute__((ext_vector_type(4))) float f32x4;    // MFMA acc
typedef __attribute__((ext_vector_type(2))) float f32x2;
typedef __attribute__((ext_vector_type(4))) unsigned short u16x4;

// aux layout (floats): [0,2N) ps per rel (rel*N+src) ; [2N,4N) pd per rel ;
//                      [4N,6N) hl per type (t*N+node) ; [6N,8N) hr per type
#define AUX_PS 0
#define AUX_PD (2 * NNODES)
#define AUX_HL (4 * NNODES)
#define AUX_HR (6 * NNODES)

// ---------- helpers ----------
__device__ __forceinline__ float elu_f(float x) { return x > 0.f ? x : (__expf(x) - 1.f); }
__device__ __forceinline__ float bf2f(unsigned short u) {
    return __uint_as_float(((unsigned)u) << 16);
}
__device__ __forceinline__ f32x2 bfp2f(unsigned p) {   // 2 packed bf16 -> 2 f32
    f32x2 r;
    r.x = __uint_as_float(p << 16);
    r.y = __uint_as_float(p & 0xffff0000u);
    return r;
}
__device__ __forceinline__ unsigned short f2bf(float f) {
    unsigned u = __float_as_uint(f);
    unsigned r = (u + 0x7fffu + ((u >> 16) & 1u)) >> 16;   // RNE
    return (unsigned short)r;
}

// ---------- f32 -> bf16 convert (hA and hB in one dispatch) ----------
__global__ __launch_bounds__(256) void conv_bf16_2(const float* __restrict__ inA,
                                                   const float* __restrict__ inB,
                                                   unsigned short* __restrict__ outA,
                                                   unsigned short* __restrict__ outB,
                                                   int half) {
    int i = (blockIdx.x * 256 + threadIdx.x) * 4;
    if (i >= 2 * half) return;
    const float* in = (i < half) ? inA : inB;
    unsigned short* out = (i < half) ? outA : outB;
    int k = (i < half) ? i : i - half;
    float4 v = *reinterpret_cast<const float4*>(&in[k]);
    u16x4 o;
    o[0] = f2bf(v.x); o[1] = f2bf(v.y); o[2] = f2bf(v.z); o[3] = f2bf(v.w);
    *reinterpret_cast<u16x4*>(&out[k]) = o;
}

// ---------- merged: precompute u_l/u_r/c_l/c_r (blocks 0-1) + weight pack (blocks 2..1537)
__global__ __launch_bounds__(256) void prep_all(
    const float* __restrict__ Wself, const float* __restrict__ Wsrc, const float* __restrict__ Wdst,
    const float* __restrict__ bself, const float* __restrict__ bsrc, const float* __restrict__ bdst,
    const float* __restrict__ Wq, const float* __restrict__ bq,
    const float* __restrict__ Wk, const float* __restrict__ bk,
    const float* __restrict__ Wal, const float* __restrict__ bal,
    const float* __restrict__ War, const float* __restrict__ bar,
    unsigned short* __restrict__ Wt, float* __restrict__ biasF,
    float* __restrict__ u_l, float* __restrict__ u_r,
    float* __restrict__ c_l, float* __restrict__ c_r) {
    if (blockIdx.x < 2) {
        int t = blockIdx.x;
        int d = threadIdx.x;
        float sl = 0.f, sr = 0.f;
        for (int j = 0; j < 64; ++j) {
            sl += Wk[((size_t)t * 256 + d) * 64 + j] * Wal[t * 64 + j];
            sr += Wq[((size_t)t * 256 + d) * 64 + j] * War[t * 64 + j];
        }
        u_l[t * 256 + d] = sl;
        u_r[t * 256 + d] = sr;
        if (d == 0) {
            float cl = bal[t], cr = bar[t];
            for (int j = 0; j < 64; ++j) {
                cl += bk[t * 64 + j] * Wal[t * 64 + j];
                cr += bq[t * 64 + j] * War[t * 64 + j];
            }
            c_l[t] = cl; c_r[t] = cr;
        }
        return;
    }
    int r = blockIdx.x - 2;        // 0..1535 = t*768 + n
    int t = r / 768;
    int n = r % 768;
    int seg = n >> 8;
    int nn = n & 255;
    const float* W; const float* bv; int ti;
    if (seg == 0)      { W = Wself; bv = bself; ti = t; }
    else if (seg == 1) { W = Wsrc;  bv = bsrc;  ti = t; }
    else               { W = Wdst;  bv = bdst;  ti = 1 - t; }
    int k = threadIdx.x;
    float val = W[(size_t)ti * 65536 + (size_t)k * 256 + nn];
    Wt[(size_t)r * 256 + k] = f2bf(val);
    if (k == 0) biasF[r] = bv[ti * 256 + nn];
}

// ---------- counting sort (both relations per dispatch) ----------
__global__ __launch_bounds__(256) void hist2(const int* __restrict__ dab,
                                             const int* __restrict__ dba,
                                             int* __restrict__ counts) {
    int e = blockIdx.x * 256 + threadIdx.x;
    if (e < NEDGES) atomicAdd(&counts[dab[e]], 1);
    else if (e < 2 * NEDGES) atomicAdd(&counts[NNODES + dba[e - NEDGES]], 1);
}

// vectorized scan: 1024 bins/block (4/thread, int4). NBINS % 4 == 0.
__global__ __launch_bounds__(256) void scan1v(const int* __restrict__ counts,
                                              int* __restrict__ incl,
                                              int* __restrict__ bsum, int n) {
    __shared__ int s[256];
    int t = threadIdx.x;
    int base = blockIdx.x * 1024 + t * 4;
    int4 v = make_int4(0, 0, 0, 0);
    if (base < n) v = *reinterpret_cast<const int4*>(&counts[base]);
    int l0 = v.x, l1 = l0 + v.y, l2 = l1 + v.z, l3 = l2 + v.w;
    s[t] = l3;
    __syncthreads();
#pragma unroll
    for (int off = 1; off < 256; off <<= 1) {
        int x = (t >= off) ? s[t - off] : 0;
        __syncthreads();
        s[t] += x;
        __syncthreads();
    }
    int ex = s[t] - l3;
    if (base < n)
        *reinterpret_cast<int4*>(&incl[base]) = make_int4(ex + l0, ex + l1, ex + l2, ex + l3);
    if (t == 255) bsum[blockIdx.x] = s[255];
}

__global__ __launch_bounds__(512) void scan2(int* __restrict__ bsum, int nb) {
    __shared__ int s[512];
    int t = threadIdx.x;
    s[t] = (t < nb) ? bsum[t] : 0;
    __syncthreads();
#pragma unroll
    for (int off = 1; off < 512; off <<= 1) {
        int x = (t >= off) ? s[t - off] : 0;
        __syncthreads();
        s[t] += x;
        __syncthreads();
    }
    if (t < nb) bsum[t] = s[t];
}

// finalize: row_start (exclusive, +sentinel at [n]), cursor copy
__global__ __launch_bounds__(256) void scan3v(const int* __restrict__ counts,
                                              int* __restrict__ incl_to_rs,   // in: incl, out: row_start
                                              const int* __restrict__ bsum,
                                              int* __restrict__ cursor, int n, int nb) {
    int base = blockIdx.x * 1024 + threadIdx.x * 4;
    if (blockIdx.x == 0 && threadIdx.x == 0) incl_to_rs[n] = bsum[nb - 1];  // sentinel = total
    if (base >= n) return;
    int bofs = (blockIdx.x > 0) ? bsum[blockIdx.x - 1] : 0;
    int4 ic = *reinterpret_cast<const int4*>(&incl_to_rs[base]);
    int4 cn = *reinterpret_cast<const int4*>(&counts[base]);
    int4 st = make_int4(bofs + ic.x - cn.x, bofs + ic.y - cn.y,
                        bofs + ic.z - cn.z, bofs + ic.w - cn.w);
    *reinterpret_cast<int4*>(&incl_to_rs[base]) = st;
    *reinterpret_cast<int4*>(&cursor[base]) = st;
}

__global__ __launch_bounds__(256) void scatter2(const int* __restrict__ sab,
                                                const int* __restrict__ dab,
                                                const int* __restrict__ sba,
                                                const int* __restrict__ dba,
                                                int* __restrict__ cursor,
                                                int* __restrict__ sorted_src) {
    int e = blockIdx.x * 256 + threadIdx.x;
    if (e < NEDGES) {
        int pos = atomicAdd(&cursor[dab[e]], 1);
        sorted_src[pos] = sab[e];
    } else if (e < 2 * NEDGES) {
        int k = e - NEDGES;
        int pos = atomicAdd(&cursor[NNODES + dba[k]], 1);
        sorted_src[pos] = sba[k];
    }
}

// ---------- fused bf16 MFMA GEMM (R7 structure: both operands via global_load_lds,
// counted-vmcnt 2-deep pipeline, aux node-dot epilogue). Known-good ~91us.
__global__ __launch_bounds__(256, 4) void gemm_mfma(
    const unsigned short* __restrict__ hAb,
    const unsigned short* __restrict__ hBb,
    const unsigned short* __restrict__ Wt,
    const float* __restrict__ biasF,
    const float* __restrict__ attn_v,
    const float* __restrict__ u_l,
    const float* __restrict__ u_r,
    unsigned short* __restrict__ bufA,
    unsigned short* __restrict__ bufB,
    float* __restrict__ aux,
    int M)
{
    __shared__ unsigned short lds[16384];   // 32 KB: 4x8KB stage bufs; reused as C tile
    const int tid = threadIdx.x;
    const int lane = tid & 63;
    const int w = tid >> 6;
    const int wm = w >> 1, wn = w & 1;

    // bijective XCD swizzle (m204)
    const int nwg = NWG_GEMM;
    const int q = nwg / 8, r = nwg % 8;
    int orig = blockIdx.x;
    int xcd = orig % 8, idx = orig / 8;
    int wgid = (xcd < r) ? (xcd * (q + 1) + idx) : (r * (q + 1) + (xcd - r) * q + idx);
    int t   = wgid / (NXP * 6);
    int rem = wgid % (NXP * 6);
    int xp  = rem / 6;
    int yc  = rem % 6;

    const int row0 = xp * 128;
    const int col0 = yc * 128;
    const unsigned short* Ain = t ? hBb : hAb;
    const unsigned short* Wtt = Wt + (size_t)t * 768 * 256;
    const float* bias = biasF + t * 768;
    unsigned short* Cout = t ? bufB : bufA;

    f32x4 acc[4][4] = {};

    const unsigned short* gA[2];
    const unsigned short* gB[2];
#pragma unroll
    for (int rr = 0; rr < 2; ++rr) {
        int qq = rr * 256 + tid;
        int row = qq >> 2;
        int c = (qq & 3) ^ ((row >> 1) & 3);
        int ga = min(row0 + row, M - 1);
        gA[rr] = Ain + (size_t)ga * 256 + c * 8;
        gB[rr] = Wtt + (size_t)(col0 + row) * 256 + c * 8;
    }

#define STAGE(buf, kt)                                                                   \
    {                                                                                    \
        unsigned short* Ad = lds + (buf) * 4096;                                         \
        unsigned short* Bd = lds + 8192 + (buf) * 4096;                                  \
        _Pragma("unroll")                                                                \
        for (int rr = 0; rr < 2; ++rr) {                                                 \
            __builtin_amdgcn_global_load_lds(                                            \
                (const __attribute__((address_space(1))) unsigned int*)(gA[rr] + (kt)),  \
                (__attribute__((address_space(3))) unsigned int*)(Ad + ((rr * 256 + w * 64) << 3)), \
                16, 0, 0);                                                               \
            __builtin_amdgcn_global_load_lds(                                            \
                (const __attribute__((address_space(1))) unsigned int*)(gB[rr] + (kt)),  \
                (__attribute__((address_space(3))) unsigned int*)(Bd + ((rr * 256 + w * 64) << 3)), \
                16, 0, 0);                                                               \
        }                                                                                \
    }

    STAGE(0, 0);        // tile 0 (4 loads/thread)
    STAGE(1, 32);       // tile 1 (8 outstanding)

#pragma unroll
    for (int it = 0; it < 8; ++it) {
        const int cur = it & 1;
        if (it < 7) { asm volatile("s_waitcnt vmcnt(4)" ::: "memory"); }
        else        { asm volatile("s_waitcnt vmcnt(0)" ::: "memory"); }
        __builtin_amdgcn_s_barrier();
        __builtin_amdgcn_sched_barrier(0);

        const unsigned short* As = lds + cur * 4096;
        const unsigned short* Bs = lds + 8192 + cur * 4096;
        short8 a[4], b[4];
#pragma unroll
        for (int i = 0; i < 4; ++i) {
            int ar = wm * 64 + i * 16 + (lane & 15);
            a[i] = *reinterpret_cast<const short8*>(
                &As[ar * 32 + (((lane >> 4) ^ ((ar >> 1) & 3)) << 3)]);
            int br = wn * 64 + i * 16 + (lane & 15);
            b[i] = *reinterpret_cast<const short8*>(
                &Bs[br * 32 + (((lane >> 4) ^ ((br >> 1) & 3)) << 3)]);
        }
#pragma unroll
        for (int i = 0; i < 4; ++i)
#pragma unroll
            for (int j = 0; j < 4; ++j)
                acc[i][j] = __builtin_amdgcn_mfma_f32_16x16x32_bf16(a[i], b[j], acc[i][j], 0, 0, 0);

        asm volatile("s_waitcnt lgkmcnt(0)" ::: "memory");
        __builtin_amdgcn_sched_barrier(0);
        __builtin_amdgcn_s_barrier();
        if (it < 6) STAGE(cur, (it + 2) * 32);
    }
#undef STAGE

    // ---- epilogue: acc (+bias) -> LDS [128][128] bf16 with per-row col-group XOR
#pragma unroll
    for (int j = 0; j < 4; ++j) {
        int colg = wn * 4 + j;
        int ci = lane & 15;
        float bv = bias[col0 + colg * 16 + ci];
#pragma unroll
        for (int i = 0; i < 4; ++i) {
            int rowb = wm * 64 + i * 16 + ((lane >> 4) << 2);
#pragma unroll
            for (int v = 0; v < 4; ++v) {
                int row = rowb + v;
                int g2 = colg ^ ((row >> 2) & 3);
                lds[row * 128 + g2 * 16 + ci] = f2bf(acc[i][j][v] + bv);
            }
        }
    }
    __syncthreads();

    const int seg = yc >> 1;                   // 0:z, 1:ftS, 2:ftD
    const float* avp1; float* axp1;
    const float* avp2 = nullptr; float* axp2 = nullptr;
    if (seg == 0) {
        avp1 = u_l + t * 256;            axp1 = aux + AUX_HL + (size_t)t * NNODES;
        avp2 = u_r + t * 256;            axp2 = aux + AUX_HR + (size_t)t * NNODES;
    } else if (seg == 1) {
        avp1 = attn_v + t * 256;         axp1 = aux + AUX_PS + (size_t)t * NNODES;
    } else {
        avp1 = attn_v + (1 - t) * 256;   axp1 = aux + AUX_PD + (size_t)(1 - t) * NNODES;
    }

#pragma unroll
    for (int p = 0; p < 8; ++p) {
        int idx = p * 256 + tid;
        int row = idx >> 4;
        int ch = idx & 15;
        int g2 = (ch >> 1) ^ ((row >> 2) & 3);
        int grow = row0 + row;
        bool ok = grow < M;
        short8 val = *reinterpret_cast<const short8*>(&lds[row * 128 + g2 * 16 + ((ch & 1) << 3)]);
        if (ok)
            *reinterpret_cast<short8*>(&Cout[(size_t)grow * 768 + col0 + ch * 8]) = val;
        int colb = (yc & 1) * 128 + ch * 8;
        float4 w0v = *reinterpret_cast<const float4*>(&avp1[colb]);
        float4 w1v = *reinterpret_cast<const float4*>(&avp1[colb + 4]);
        float p1 = w0v.x * bf2f((unsigned short)val[0]) + w0v.y * bf2f((unsigned short)val[1])
                 + w0v.z * bf2f((unsigned short)val[2]) + w0v.w * bf2f((unsigned short)val[3])
                 + w1v.x * bf2f((unsigned short)val[4]) + w1v.y * bf2f((unsigned short)val[5])
                 + w1v.z * bf2f((unsigned short)val[6]) + w1v.w * bf2f((unsigned short)val[7]);
        p1 += __shfl_xor(p1, 1);
        p1 += __shfl_xor(p1, 2);
        p1 += __shfl_xor(p1, 4);
        p1 += __shfl_xor(p1, 8);
        if ((tid & 15) == 0 && ok) atomicAdd(&axp1[grow], p1);
        if (avp2) {
            float4 y0 = *reinterpret_cast<const float4*>(&avp2[colb]);
            float4 y1 = *reinterpret_cast<const float4*>(&avp2[colb + 4]);
            float p2 = y0.x * bf2f((unsigned short)val[0]) + y0.y * bf2f((unsigned short)val[1])
                     + y0.z * bf2f((unsigned short)val[2]) + y0.w * bf2f((unsigned short)val[3])
                     + y1.x * bf2f((unsigned short)val[4]) + y1.y * bf2f((unsigned short)val[5])
                     + y1.z * bf2f((unsigned short)val[6]) + y1.w * bf2f((unsigned short)val[7]);
            p2 += __shfl_xor(p2, 1);
            p2 += __shfl_xor(p2, 2);
            p2 += __shfl_xor(p2, 4);
            p2 += __shfl_xor(p2, 8);
            if ((tid & 15) == 0 && ok) atomicAdd(&axp2[grow], p2);
        }
    }
}

// ---------- fully fused per-dst GATv2 + node attention + combine
// 16 lanes/dst, 4 dsts/wave. lrelu factorization: logit = 0.6(ps+pd) + 0.4*sum(av*|fs+fd|).
// batch-4 gather loads (MLP) with batch-2 processing. cnt from row_start diff.
__global__ __launch_bounds__(256) void gat_fused(
    const unsigned short* __restrict__ bufA, const unsigned short* __restrict__ bufB,
    const int* __restrict__ sorted_src, const int* __restrict__ row_start,
    const float* __restrict__ attn_v, const float* __restrict__ gbias,
    const float* __restrict__ u_l,
    const float* __restrict__ c_l, const float* __restrict__ c_r,
    const float* __restrict__ aux,
    float* __restrict__ out)
{
    const int tid = threadIdx.x;
    const int l = tid & 15;            // lane in 16-group
    const int gBase = tid & 48;        // group base lane within wave
    const int nd = blockIdx.x * 16 + (tid >> 4);
    if (nd >= 2 * NNODES) return;
    const int rel = nd >= NNODES;      // 0: ab (dst type B), 1: ba (dst type A)
    const int d = nd - rel * NNODES;
    const int td = rel ? 0 : 1;        // dst node type

    const unsigned short* zbuf = td ? bufB : bufA;
    const unsigned short* ftS = (rel ? bufB : bufA) + 256;
    const unsigned short* ftD = zbuf + 512;
    const float clv = c_l[td], crv = c_r[td];

    // per-lane dims [l*16, l*16+16) as f32x2 pairs
    f32x2 fd2[8], av2[8];
    {
        const unsigned short* fdp = &ftD[(size_t)d * 768 + l * 16];
        uint4 d0 = *reinterpret_cast<const uint4*>(fdp);
        uint4 d1 = *reinterpret_cast<const uint4*>(fdp + 8);
        fd2[0] = bfp2f(d0.x); fd2[1] = bfp2f(d0.y); fd2[2] = bfp2f(d0.z); fd2[3] = bfp2f(d0.w);
        fd2[4] = bfp2f(d1.x); fd2[5] = bfp2f(d1.y); fd2[6] = bfp2f(d1.z); fd2[7] = bfp2f(d1.w);
        const float* avp = attn_v + rel * 256 + l * 16;
#pragma unroll
        for (int e = 0; e < 4; ++e) {
            float4 a = *reinterpret_cast<const float4*>(&avp[e * 4]);
            av2[2 * e].x = a.x; av2[2 * e].y = a.y;
            av2[2 * e + 1].x = a.z; av2[2 * e + 1].y = a.w;
        }
    }

    const float pd6 = 0.6f * aux[AUX_PD + (size_t)rel * NNODES + d];
    const float hlv = aux[AUX_HL + (size_t)td * NNODES + d] + clv;
    const float hrv = aux[AUX_HR + (size_t)td * NNODES + d] + crv;
    const float a0 = elu_f(hlv + hrv);           // att_self (pre-softmax)
    const float* psb = aux + AUX_PS + (size_t)rel * NNODES;

    const int p0  = row_start[nd];
    const int cnt = row_start[nd + 1] - p0;
    float den = 0.f;
    f32x2 acc2[8];
#pragma unroll
    for (int e = 0; e < 8; ++e) { acc2[e].x = 0.f; acc2[e].y = 0.f; }

// process two edges from raw uint4 regs
#define PROC2(X0, X1, QX, Y0, Y1, QY)                                            \
    {                                                                            \
        f32x2 fa2[8], fb2[8];                                                    \
        fa2[0] = bfp2f((X0).x); fa2[1] = bfp2f((X0).y);                          \
        fa2[2] = bfp2f((X0).z); fa2[3] = bfp2f((X0).w);                          \
        fa2[4] = bfp2f((X1).x); fa2[5] = bfp2f((X1).y);                          \
        fa2[6] = bfp2f((X1).z); fa2[7] = bfp2f((X1).w);                          \
        fb2[0] = bfp2f((Y0).x); fb2[1] = bfp2f((Y0).y);                          \
        fb2[2] = bfp2f((Y0).z); fb2[3] = bfp2f((Y0).w);                          \
        fb2[4] = bfp2f((Y1).x); fb2[5] = bfp2f((Y1).y);                          \
        fb2[6] = bfp2f((Y1).z); fb2[7] = bfp2f((Y1).w);                          \
        float Sa = 0.f, Sb = 0.f;                                                \
        _Pragma("unroll")                                                        \
        for (int e = 0; e < 8; ++e) {                                            \
            f32x2 xa = fa2[e] + fd2[e];                                          \
            f32x2 xb = fb2[e] + fd2[e];                                          \
            Sa += av2[e].x * fabsf(xa.x);                                        \
            Sa += av2[e].y * fabsf(xa.y);                                        \
            Sb += av2[e].x * fabsf(xb.x);                                        \
            Sb += av2[e].y * fabsf(xb.y);                                        \
        }                                                                        \
        Sa += __shfl_xor(Sa, 1); Sb += __shfl_xor(Sb, 1);                        \
        Sa += __shfl_xor(Sa, 2); Sb += __shfl_xor(Sb, 2);                        \
        Sa += __shfl_xor(Sa, 4); Sb += __shfl_xor(Sb, 4);                        \
        Sa += __shfl_xor(Sa, 8); Sb += __shfl_xor(Sb, 8);                        \
        float wa = __expf(fmaf(0.6f, (QX), pd6) + 0.4f * Sa);                    \
        float wb = __expf(fmaf(0.6f, (QY), pd6) + 0.4f * Sb);                    \
        den += wa + wb;                                                          \
        _Pragma("unroll")                                                        \
        for (int e = 0; e < 8; ++e) acc2[e] += wa * fa2[e] + wb * fb2[e];        \
    }

    for (int base = 0; base < cnt; base += 16) {
        int nloc = min(16, cnt - base);
        int sv = 0; float psl = 0.f;
        if (base + l < cnt) { sv = sorted_src[p0 + base + l]; psl = psb[sv]; }
        int j = 0;
        for (; j + 4 <= nloc; j += 4) {   // issue 4 edges' loads, process 2+2
            int s0 = __shfl(sv, gBase + j);
            int s1 = __shfl(sv, gBase + j + 1);
            int s2 = __shfl(sv, gBase + j + 2);
            int s3 = __shfl(sv, gBase + j + 3);
            float q0 = __shfl(psl, gBase + j);
            float q1 = __shfl(psl, gBase + j + 1);
            float q2 = __shfl(psl, gBase + j + 2);
            float q3 = __shfl(psl, gBase + j + 3);
            const unsigned short* rp0 = &ftS[(size_t)s0 * 768 + l * 16];
            const unsigned short* rp1 = &ftS[(size_t)s1 * 768 + l * 16];
            const unsigned short* rp2 = &ftS[(size_t)s2 * 768 + l * 16];
            const unsigned short* rp3 = &ftS[(size_t)s3 * 768 + l * 16];
            uint4 A0 = *reinterpret_cast<const uint4*>(rp0);
            uint4 A1 = *reinterpret_cast<const uint4*>(rp0 + 8);
            uint4 B0 = *reinterpret_cast<const uint4*>(rp1);
            uint4 B1 = *reinterpret_cast<const uint4*>(rp1 + 8);
            uint4 C0 = *reinterpret_cast<const uint4*>(rp2);
            uint4 C1 = *reinterpret_cast<const uint4*>(rp2 + 8);
            uint4 D0 = *reinterpret_cast<const uint4*>(rp3);
            uint4 D1 = *reinterpret_cast<const uint4*>(rp3 + 8);
            PROC2(A0, A1, q0, B0, B1, q1);
            PROC2(C0, C1, q2, D0, D1, q3);
        }
        for (; j + 2 <= nloc; j += 2) {
            int s0 = __shfl(sv, gBase + j);
            int s1 = __shfl(sv, gBase + j + 1);
            float q0 = __shfl(psl, gBase + j);
            float q1 = __shfl(psl, gBase + j + 1);
            const unsigned short* rp0 = &ftS[(size_t)s0 * 768 + l * 16];
            const unsigned short* rp1 = &ftS[(size_t)s1 * 768 + l * 16];
            uint4 A0 = *reinterpret_cast<const uint4*>(rp0);
            uint4 A1 = *reinterpret_cast<const uint4*>(rp0 + 8);
            uint4 B0 = *reinterpret_cast<const uint4*>(rp1);
            uint4 B1 = *reinterpret_cast<const uint4*>(rp1 + 8);
            PROC2(A0, A1, q0, B0, B1, q1);
        }
        if (j < nloc) {
            int s0 = __shfl(sv, gBase + j);
            float q0 = __shfl(psl, gBase + j);
            const unsigned short* rp0 = &ftS[(size_t)s0 * 768 + l * 16];
            uint4 A0 = *reinterpret_cast<const uint4*>(rp0);
            uint4 A1 = *reinterpret_cast<const uint4*>(rp0 + 8);
            f32x2 fa2[8];
            fa2[0] = bfp2f(A0.x); fa2[1] = bfp2f(A0.y); fa2[2] = bfp2f(A0.z); fa2[3] = bfp2f(A0.w);
            fa2[4] = bfp2f(A1.x); fa2[5] = bfp2f(A1.y); fa2[6] = bfp2f(A1.z); fa2[7] = bfp2f(A1.w);
            float Sa = 0.f;
#pragma unroll
            for (int e = 0; e < 8; ++e) {
                f32x2 xa = fa2[e] + fd2[e];
                Sa += av2[e].x * fabsf(xa.x);
                Sa += av2[e].y * fabsf(xa.y);
            }
            Sa += __shfl_xor(Sa, 1);
            Sa += __shfl_xor(Sa, 2);
            Sa += __shfl_xor(Sa, 4);
            Sa += __shfl_xor(Sa, 8);
            float wa = __expf(fmaf(0.6f, q0, pd6) + 0.4f * Sa);
            den += wa;
#pragma unroll
            for (int e = 0; e < 8; ++e) acc2[e] += wa * fa2[e];
        }
    }
#undef PROC2

    // ---- finalize rst row: v = acc/den + gbias
    float inv = den > 0.f ? 1.f / den : 1.f;
    const float* gb = gbias + rel * 256 + l * 16;
    const float* ulp = u_l + td * 256 + l * 16;
    f32x2 v2[8];
    float dotv = 0.f;
#pragma unroll
    for (int e = 0; e < 4; ++e) {
        float4 g = *reinterpret_cast<const float4*>(&gb[e * 4]);
        float4 u = *reinterpret_cast<const float4*>(&ulp[e * 4]);
        v2[2 * e].x     = acc2[2 * e].x     * inv + g.x;
        v2[2 * e].y     = acc2[2 * e].y     * inv + g.y;
        v2[2 * e + 1].x = acc2[2 * e + 1].x * inv + g.z;
        v2[2 * e + 1].y = acc2[2 * e + 1].y * inv + g.w;
        dotv += v2[2 * e].x * u.x + v2[2 * e].y * u.y
              + v2[2 * e + 1].x * u.z + v2[2 * e + 1].y * u.w;
    }
    dotv += __shfl_xor(dotv, 1);
    dotv += __shfl_xor(dotv, 2);
    dotv += __shfl_xor(dotv, 4);
    dotv += __shfl_xor(dotv, 8);
    const float ea = elu_f(dotv + clv + hrv);

    // ---- 2-way softmax combine + final elu, write output row
    float mx = fmaxf(a0, ea);
    float e0 = __expf(a0 - mx), e1 = __expf(ea - mx);
    float is = 1.f / (e0 + e1);
    float w0 = e0 * is, w1 = e1 * is;

    const unsigned short* zrow = zbuf + (size_t)d * 768 + l * 16;
    uint4 z0 = *reinterpret_cast<const uint4*>(zrow);
    uint4 z1 = *reinterpret_cast<const uint4*>(zrow + 8);
    f32x2 zf2[8];
    zf2[0] = bfp2f(z0.x); zf2[1] = bfp2f(z0.y); zf2[2] = bfp2f(z0.z); zf2[3] = bfp2f(z0.w);
    zf2[4] = bfp2f(z1.x); zf2[5] = bfp2f(z1.y); zf2[6] = bfp2f(z1.z); zf2[7] = bfp2f(z1.w);

    float* orow = out + ((size_t)(1 - rel) * NNODES + d) * 256 + l * 16;
#pragma unroll
    for (int e = 0; e < 4; ++e) {
        float4 o;
        o.x = elu_f(w0 * zf2[2 * e].x     + w1 * v2[2 * e].x);
        o.y = elu_f(w0 * zf2[2 * e].y     + w1 * v2[2 * e].y);
        o.z = elu_f(w0 * zf2[2 * e + 1].x + w1 * v2[2 * e + 1].x);
        o.w = elu_f(w0 * zf2[2 * e + 1].y + w1 * v2[2 * e + 1].y);
        *reinterpret_cast<float4*>(&orow[e * 4]) = o;
    }
}

extern "C" void kernel_launch(void* const* d_in, const int* in_sizes, int n_in,
                              void* d_out, int out_size, void* d_ws, size_t ws_size,
                              hipStream_t stream) {
    const float* hA     = (const float*)d_in[0];
    const float* hB     = (const float*)d_in[1];
    const float* Wself  = (const float*)d_in[2];
    const float* bself  = (const float*)d_in[3];
    const float* Wq     = (const float*)d_in[4];
    const float* bq     = (const float*)d_in[5];
    const float* Wk     = (const float*)d_in[6];
    const float* bk     = (const float*)d_in[7];
    const float* Wal    = (const float*)d_in[8];
    const float* bal    = (const float*)d_in[9];
    const float* War    = (const float*)d_in[10];
    const float* bar    = (const float*)d_in[11];
    const float* Wsrc   = (const float*)d_in[12];
    const float* bsrc   = (const float*)d_in[13];
    const float* Wdst   = (const float*)d_in[14];
    const float* bdst   = (const float*)d_in[15];
    const float* attn_v = (const float*)d_in[16];
    const float* gbias  = (const float*)d_in[17];
    const int* eab_src  = (const int*)d_in[18];
    const int* eab_dst  = (const int*)d_in[19];
    const int* eba_src  = (const int*)d_in[20];
    const int* eba_dst  = (const int*)d_in[21];
    float* out = (float*)d_out;
    char* ws = (char*)d_ws;

    // ---- workspace layout (256B-aligned blocks)
    const size_t SZ_BUF = (size_t)NNODES * 768 * sizeof(unsigned short);  // 76.8 MB
    const size_t SZ_H   = (size_t)NNODES * 256 * sizeof(unsigned short);  // 25.6 MB
    size_t off = 0;
    auto alloc = [&](size_t bytes) { void* p = ws + off; off = (off + bytes + 255) & ~(size_t)255; return p; };
    unsigned short* bufA = (unsigned short*)alloc(SZ_BUF);  // [z0 | ftS_ab | ftD_ba]
    unsigned short* bufB = (unsigned short*)alloc(SZ_BUF);  // [z1 | ftS_ba | ftD_ab]
    unsigned short* hAb  = (unsigned short*)alloc(SZ_H);
    unsigned short* hBb  = (unsigned short*)alloc(SZ_H);
    unsigned short* Wt   = (unsigned short*)alloc(2 * 768 * 256 * sizeof(unsigned short));
    float* biasF   = (float*)alloc(2 * 768 * sizeof(float));
    float* aux     = (float*)alloc((size_t)8 * NNODES * sizeof(float));   // ps|pd|hl|hr
    int* counts    = (int*)alloc(NBINS * sizeof(int));
    int* row_start = (int*)alloc((NBINS + 4) * sizeof(int));              // +sentinel
    int* cursor    = (int*)alloc(NBINS * sizeof(int));
    int* bsum      = (int*)alloc(512 * sizeof(int));
    int* sorted_src= (int*)alloc(2 * (size_t)NEDGES * sizeof(int));
    float* u_l     = (float*)alloc(2 * 256 * sizeof(float));
    float* u_r     = (float*)alloc(2 * 256 * sizeof(float));
    float* c_l     = (float*)alloc(2 * sizeof(float));
    float* c_r     = (float*)alloc(2 * sizeof(float));

    hipMemsetAsync(counts, 0, NBINS * sizeof(int), stream);
    hipMemsetAsync(aux, 0, (size_t)8 * NNODES * sizeof(float), stream);

    // ---- bf16 conversions + merged weight pack / uv precompute
    const int HN = NNODES * 256;
    conv_bf16_2<<<(2 * HN / 4 + 255) / 256, 256, 0, stream>>>(hA, hB, hAb, hBb, HN);
    prep_all<<<2 + 2 * 768, 256, 0, stream>>>(Wself, Wsrc, Wdst, bself, bsrc, bdst,
                                              Wq, bq, Wk, bk, Wal, bal, War, bar,
                                              Wt, biasF, u_l, u_r, c_l, c_r);

    // ---- counting sort of edges by dst (bins: [0,N)=ab, [N,2N)=ba)
    const int e2blocks = (2 * NEDGES + 255) / 256;
    hist2<<<e2blocks, 256, 0, stream>>>(eab_dst, eba_dst, counts);
    const int sblocks = (NBINS + 1023) / 1024;   // 98
    scan1v<<<sblocks, 256, 0, stream>>>(counts, row_start, bsum, NBINS);
    scan2<<<1, 512, 0, stream>>>(bsum, sblocks);
    scan3v<<<sblocks, 256, 0, stream>>>(counts, row_start, bsum, cursor, NBINS, sblocks);
    scatter2<<<e2blocks, 256, 0, stream>>>(eab_src, eab_dst, eba_src, eba_dst, cursor, sorted_src);

    // ---- fused MFMA GEMM (both types, one dispatch) + aux node-dots
    gemm_mfma<<<NWG_GEMM, 256, 0, stream>>>(hAb, hBb, Wt, biasF, attn_v, u_l, u_r,
                                            bufA, bufB, aux, NNODES);

    // ---- fully fused GAT + node attention + combine
    gat_fused<<<(2 * NNODES + 15) / 16, 256, 0, stream>>>(bufA, bufB, sorted_src, row_start,
                                                          attn_v, gbias, u_l,
                                                          c_l, c_r, aux, out);
}